// Round 11
// baseline (1580.406 us; speedup 1.0000x reference)
//
#include <hip/hip_runtime.h>
#include <math.h>

namespace {

constexpr int Bn = 4;
constexpr int H0 = 256, W0 = 448;
constexpr int H1 = 128, W1 = 224;
constexpr int H2 = 64,  W2 = 112;
constexpr int HW0 = H0 * W0;
constexpr int CAP = 8192;        // cleanup-list capacity

// np.linspace(-1+1/n, 1-1/n, n, dtype=f32) bit path (backwarp side; validated).
__device__ inline float lin_ac_f32(int i, int n) {
    if (i == n - 1) return (float)(1.0 - 1.0 / (double)n);
    double start = -1.0 + 1.0 / (double)n;
    double step  = (2.0 - 2.0 / (double)n) / (double)(n - 1);
    return (float)(start + (double)i * step);
}

// ---------------------------------------------------------------------------
// Backwarp + L1 occlusion metric (validated, unchanged).
// ---------------------------------------------------------------------------
__global__ void metric_kernel(const float* __restrict__ imgA,
                              const float* __restrict__ imgB,
                              const float* __restrict__ flow,
                              float* __restrict__ mout) {
    int idx = blockIdx.x * blockDim.x + threadIdx.x;
    int total = Bn * HW0;
    if (idx >= total) return;
    int x = idx % W0;
    int y = (idx / W0) % H0;
    int b = idx / HW0;

    const float* fb = flow + (size_t)b * 2 * HW0;
    float fx = fb[y * W0 + x];
    float fy = fb[(size_t)HW0 + y * W0 + x];

    const float sxc = (float)(2.0 / (double)(W0 - 1));
    const float syc = (float)(2.0 / (double)(H0 - 1));
    float gx = __fadd_rn(lin_ac_f32(x, W0), __fmul_rn(fx, sxc));
    float gy = __fadd_rn(lin_ac_f32(y, H0), __fmul_rn(fy, syc));
    float px = __fmul_rn(__fmul_rn(__fadd_rn(gx, 1.0f), 0.5f), (float)(W0 - 1));
    float py = __fmul_rn(__fmul_rn(__fadd_rn(gy, 1.0f), 0.5f), (float)(H0 - 1));

    float x0f = floorf(px), y0f = floorf(py);
    float x1f = x0f + 1.0f, y1f = y0f + 1.0f;
    int x0 = (int)x0f, y0 = (int)y0f, x1 = (int)x1f, y1 = (int)y1f;

    float tw[4] = { (x1f - px) * (y1f - py), (px - x0f) * (y1f - py),
                    (x1f - px) * (py - y0f), (px - x0f) * (py - y0f) };
    int tx[4] = { x0, x1, x0, x1 };
    int ty[4] = { y0, y0, y1, y1 };

    const float* ib = imgB + (size_t)b * 3 * HW0;
    float acc0 = 0.f, acc1 = 0.f, acc2 = 0.f;
#pragma unroll
    for (int t = 0; t < 4; ++t) {
        bool valid = (tx[t] >= 0) && (tx[t] < W0) && (ty[t] >= 0) && (ty[t] < H0);
        int xc = min(max(tx[t], 0), W0 - 1);
        int yc = min(max(ty[t], 0), H0 - 1);
        float ww = valid ? tw[t] : 0.f;
        int off = yc * W0 + xc;
        acc0 += ib[off] * ww;
        acc1 += ib[(size_t)HW0 + off] * ww;
        acc2 += ib[(size_t)2 * HW0 + off] * ww;
    }
    const float* ia = imgA + (size_t)b * 3 * HW0;
    int off = y * W0 + x;
    float m = (fabsf(ia[off] - acc0) +
               fabsf(ia[(size_t)HW0 + off] - acc1) +
               fabsf(ia[(size_t)2 * HW0 + off] - acc2)) * (1.f / 3.f);
    mout[idx] = m;
}

// jax-f32 linspace bit path + endpoint forcing (validated round 6).
__device__ inline void ac32_iota(int i, int n_in, int n_out, float delta,
                                 int& i0, int& i1, float& fr) {
    float v = (i == n_out - 1) ? (float)(n_in - 1) : __fmul_rn(delta, (float)i);
    float f0 = floorf(v);
    i0 = (int)f0;
    i1 = min(i0 + 1, n_in - 1);
    fr = __fsub_rn(v, f0);
}

// Unfused pinned f32 bilinear (validated round 6).
__device__ inline float bilerp32(const float* __restrict__ s, int Win,
                                 int y0, int y1, int x0, int x1,
                                 float wy, float wx) {
    float a = s[y0 * Win + x0], b = s[y1 * Win + x0];
    float c = s[y0 * Win + x1], d = s[y1 * Win + x1];
    float omwy = __fsub_rn(1.0f, wy), omwx = __fsub_rn(1.0f, wx);
    float r0 = __fadd_rn(__fmul_rn(a, omwy), __fmul_rn(b, wy));
    float r1 = __fadd_rn(__fmul_rn(c, omwy), __fmul_rn(d, wy));
    return __fadd_rn(__fmul_rn(r0, omwx), __fmul_rn(r1, wx));
}

// chunked XCD swizzle (grid divisible by 8)
__device__ inline int swz_block(int bid, int nblk) {
    int cpx = nblk >> 3;
    return (bid & 7) * cpx + (bid >> 3);
}

// ---------------------------------------------------------------------------
// Shared tap geometry — EXACT round-6 bit paths (validated).
// ---------------------------------------------------------------------------
template<int LVL, int D>
struct Geo {
    int   tx[4], ty[4];
    float tw[4];
    bool  reg;
    int   ry0, ry1, rx0, rx1;
    float wy, wx;
};

template<int LVL, int D>
__device__ inline Geo<LVL, D> geom(int x, int y, int b, int h, int w,
                                   const float* __restrict__ flow,
                                   float scale, float dly, float dlx) {
    Geo<LVL, D> g;
    float gx, gy, x0f, y0f, x1f, y1f;
    if constexpr (LVL == 0) {
        const float* fb = flow + (size_t)b * 2 * HW0;
        float fx = 0.5f * fb[y * W0 + x];
        float fy = 0.5f * fb[(size_t)HW0 + y * W0 + x];
        gx = (float)x + fx;
        gy = (float)y + fy;
        x0f = floorf(gx); y0f = floorf(gy);
        x1f = x0f + 1.f;  y1f = y0f + 1.f;
        g.tw[0] = (x1f - gx) * (y1f - gy); g.tw[1] = (gx - x0f) * (y1f - gy);
        g.tw[2] = (x1f - gx) * (gy - y0f); g.tw[3] = (gx - x0f) * (gy - y0f);
    } else {
        ac32_iota(y, H0, h, dly, g.ry0, g.ry1, g.wy);
        ac32_iota(x, W0, w, dlx, g.rx0, g.rx1, g.wx);
        const float* fB = flow + (size_t)b * 2 * HW0;
        float fx = __fmul_rn(bilerp32(fB, W0, g.ry0, g.ry1, g.rx0, g.rx1, g.wy, g.wx), scale);
        float fy = __fmul_rn(bilerp32(fB + (size_t)HW0, W0, g.ry0, g.ry1, g.rx0, g.rx1, g.wy, g.wx), scale);
        gx = __fadd_rn((float)x, fx);
        gy = __fadd_rn((float)y, fy);
        x0f = floorf(gx); y0f = floorf(gy);
        x1f = __fadd_rn(x0f, 1.0f); y1f = __fadd_rn(y0f, 1.0f);
        float dx0 = __fsub_rn(x1f, gx), dx1 = __fsub_rn(gx, x0f);
        float dy0 = __fsub_rn(y1f, gy), dy1 = __fsub_rn(gy, y0f);
        g.tw[0] = __fmul_rn(dx0, dy0); g.tw[1] = __fmul_rn(dx1, dy0);
        g.tw[2] = __fmul_rn(dx0, dy1); g.tw[3] = __fmul_rn(dx1, dy1);
    }
    int x0 = (int)x0f, y0 = (int)y0f;
    g.tx[0] = x0;     g.tx[1] = x0 + 1; g.tx[2] = x0;     g.tx[3] = x0 + 1;
    g.ty[0] = y0;     g.ty[1] = y0;     g.ty[2] = y0 + 1; g.ty[3] = y0 + 1;
    g.reg = (x0 >= x - D) && (x0 + 1 <= x + D) && (y0 >= y - D) && (y0 + 1 <= y + D);
    return g;
}

// ---------------------------------------------------------------------------
// Cleanup: irregular (|disp|>D) sources -> compact global list.
// ---------------------------------------------------------------------------
template<int LVL, int CB, int D>
__global__ __launch_bounds__(256) void cleanup_kernel(
        const float* __restrict__ img, const float* __restrict__ feat,
        const float* __restrict__ flow, const float* __restrict__ met,
        const float* __restrict__ alphap,
        int* __restrict__ cnt, float* __restrict__ list,
        int h, int w, float scale, float dly, float dlx) {
    int idx = blockIdx.x * 256 + threadIdx.x;
    int hw = h * w;
    if (idx >= Bn * hw) return;
    int x = idx % w, y = (idx / w) % h, b = idx / hw;

    Geo<LVL, D> g = geom<LVL, D>(x, y, b, h, w, flow, scale, dly, dlx);
    if (g.reg) return;

    float a = alphap[0];
    float wgt;
    if constexpr (LVL == 0) wgt = expf(a * met[(size_t)b * HW0 + y * W0 + x]);
    else {
        float m = bilerp32(met + (size_t)b * HW0, W0, g.ry0, g.ry1, g.rx0, g.rx1, g.wy, g.wx);
        wgt = expf(__fmul_rn(a, m));
    }
    int sidx = y * w + x;
#pragma unroll
    for (int t = 0; t < 4; ++t) {
        bool valid = (g.tx[t] >= 0) && (g.tx[t] < w) && (g.ty[t] >= 0) && (g.ty[t] < h);
        if (!valid) continue;
        int pos = atomicAdd(cnt, 1);
        if (pos >= CAP) continue;
        float* en = list + (size_t)pos * (CB + 2);
        en[0] = __int_as_float(b * hw + g.ty[t] * w + g.tx[t]);
        if constexpr (LVL == 0) {
            float twv = g.tw[t] * wgt;
            en[1] = twv;
            for (int c = 0; c < CB; ++c) {
                float v = (c < 3) ? img[((size_t)b * 3 + c) * hw + sidx]
                                  : feat[((size_t)b * 32 + (c - 3)) * hw + sidx];
                en[2 + c] = v * twv;
            }
        } else {
            en[1] = __fmul_rn(wgt, g.tw[t]);
            for (int c = 0; c < CB; ++c) {
                float v = feat[((size_t)b * CB + c) * hw + sidx];
                en[2 + c] = __fmul_rn(__fmul_rn(v, wgt), g.tw[t]);
            }
        }
    }
}

// ---------------------------------------------------------------------------
// Tile-owned splat, two-phase:
//  P1: window scan, geometry only; weight taps accumulated; hitting taps
//      ballot-compacted into an LDS queue (packed (sidx<<8)|lidx + weights).
//  P2: dense (channel x entry) sweep, all 64 lanes active: load, mul, ds-add.
// Multiply orders preserved exactly: L0 add = v*(tw*wgt); L>=1 add=(v*wgt)*tw.
// ---------------------------------------------------------------------------
template<int LVL, int CB, int TH, int TW, int D, int NT, int QCAP>
__global__ __launch_bounds__(NT) void splat_tile(
        const float* __restrict__ img, const float* __restrict__ feat,
        const float* __restrict__ flow, const float* __restrict__ met,
        const float* __restrict__ alphap,
        const int* __restrict__ cnt, const float* __restrict__ list,
        float* __restrict__ outp, int Cout, int cbase,
        int h, int w, float scale, float dly, float dlx) {
    constexpr int CV = CB + 1;
    constexpr int TPIX = TH * TW;
    __shared__ float tile[CV * TPIX];
    __shared__ int   qpacked[QCAP];
    __shared__ float qtw[QCAP];
    __shared__ float qwgt[(LVL == 0) ? 1 : QCAP];
    __shared__ int   qcnt;

    const int hw = h * w;
    const int tilesX = w / TW, tilesY = h / TH;
    int s = swz_block(blockIdx.x, gridDim.x);
    int tpb = tilesX * tilesY;
    int b = s / tpb, r = s % tpb;
    int ty0 = (r / tilesX) * TH, tx0 = (r % tilesX) * TW;
    int tid = threadIdx.x;
    int lane = tid & 63;

    for (int i = tid; i < CV * TPIX; i += NT) tile[i] = 0.f;
    if (tid == 0) qcnt = 0;
    __syncthreads();

    float a = alphap[0];
    const int Wh = TH + 2 * D, Ww = TW + 2 * D;
    const int wy0 = ty0 - D, wx0 = tx0 - D;

    // ---- phase 1: geometry scan + weight taps + queue compaction ----
    for (int i = tid; i < Wh * Ww; i += NT) {
        int sy = wy0 + i / Ww, sx = wx0 + i % Ww;
        if (sy < 0 || sy >= h || sx < 0 || sx >= w) continue;

        Geo<LVL, D> g = geom<LVL, D>(sx, sy, b, h, w, flow, scale, dly, dlx);

        int lidx[4]; int nact = 0;
#pragma unroll
        for (int t = 0; t < 4; ++t) {
            bool in = g.reg && g.tx[t] >= tx0 && g.tx[t] < tx0 + TW &&
                      g.ty[t] >= ty0 && g.ty[t] < ty0 + TH;
            lidx[t] = in ? ((g.ty[t] - ty0) * TW + (g.tx[t] - tx0)) : -1;
            nact += in;
        }
        if (!nact) continue;

        float wgt;
        if constexpr (LVL == 0) wgt = expf(a * met[(size_t)b * HW0 + sy * W0 + sx]);
        else {
            float m = bilerp32(met + (size_t)b * HW0, W0, g.ry0, g.ry1, g.rx0, g.rx1, g.wy, g.wx);
            wgt = expf(__fmul_rn(a, m));
        }

        int sidx = sy * w + sx;
#pragma unroll
        for (int t = 0; t < 4; ++t) {
            bool ht = lidx[t] >= 0;
            unsigned long long m = __ballot(ht);
            if (!m) continue;
            int ldr = (int)__builtin_ctzll(m);
            int base = 0;
            if (lane == ldr) base = atomicAdd(&qcnt, (int)__popcll(m));
            base = __shfl(base, ldr);
            if (ht) {
                float twv = (LVL == 0) ? g.tw[t] * wgt : __fmul_rn(wgt, g.tw[t]);
                atomicAdd(&tile[CB * TPIX + lidx[t]], twv);
                int pos = base + (int)__popcll(m & ((1ull << lane) - 1));
                if (pos < QCAP) {
                    qpacked[pos] = (sidx << 8) | lidx[t];
                    if constexpr (LVL == 0) qtw[pos] = twv;
                    else { qtw[pos] = g.tw[t]; qwgt[pos] = wgt; }
                }
            }
        }
    }
    __syncthreads();

    // ---- phase 2: dense (channel x entry) value accumulation ----
    int n = min(qcnt, QCAP);
    for (int c = 0; c < CB; ++c) {
        const float* sp;
        if constexpr (LVL == 0)
            sp = (c < 3) ? img + ((size_t)b * 3 + c) * hw
                         : feat + ((size_t)b * 32 + (c - 3)) * hw;
        else
            sp = feat + ((size_t)b * CB + c) * hw;
        float* tp = &tile[c * TPIX];
        for (int e = tid; e < n; e += NT) {
            int pk = qpacked[e];
            int li = pk & 255;
            int si = pk >> 8;
            float v = sp[si];
            float add;
            if constexpr (LVL == 0) add = __fmul_rn(v, qtw[e]);
            else add = __fmul_rn(__fmul_rn(v, qwgt[e]), qtw[e]);
            atomicAdd(&tp[li], add);
        }
    }
    __syncthreads();

    // ---- merge cleanup entries (uniform small count) ----
    int nc = min(cnt[0], CAP);
    if (nc > 0) {
        for (int e = tid; e < nc; e += NT) {
            const float* en = list + (size_t)e * (CB + 2);
            int tgt = __float_as_int(en[0]);
            int eb = tgt / hw, ep = tgt % hw;
            int py = ep / w, px = ep % w;
            if (eb == b && py >= ty0 && py < ty0 + TH && px >= tx0 && px < tx0 + TW) {
                int l = (py - ty0) * TW + (px - tx0);
                atomicAdd(&tile[CB * TPIX + l], en[1]);
                for (int c = 0; c < CB; ++c) atomicAdd(&tile[c * TPIX + l], en[2 + c]);
            }
        }
        __syncthreads();
    }

    // ---- normalize + store NCHW ----
    for (int p = tid; p < TPIX; p += NT) {
        float denom = tile[CB * TPIX + p] + 1e-7f;
        int gp = (ty0 + p / TW) * w + (tx0 + p % TW);
        float* ob = outp + ((size_t)b * Cout + cbase) * hw + gp;
        for (int c = 0; c < CB; ++c)
            ob[(size_t)c * hw] = tile[c * TPIX + p] / denom;
    }
}

inline int nblk(long long n) { return (int)((n + 255) / 256); }

} // namespace

extern "C" void kernel_launch(void* const* d_in, const int* in_sizes, int n_in,
                              void* d_out, int out_size, void* d_ws, size_t ws_size,
                              hipStream_t stream) {
    const float* img1 = (const float*)d_in[0];
    const float* img2 = (const float*)d_in[1];
    const float* f1_1 = (const float*)d_in[2];
    const float* f1_2 = (const float*)d_in[3];
    const float* f1_3 = (const float*)d_in[4];
    const float* f2_1 = (const float*)d_in[5];
    const float* f2_2 = (const float*)d_in[6];
    const float* f2_3 = (const float*)d_in[7];
    const float* fl12 = (const float*)d_in[8];
    const float* fl21 = (const float*)d_in[9];
    const float* alpha = (const float*)d_in[10];
    float* out = (float*)d_out;

    const float dy1 = (float)(H0 - 1) / (float)(H1 - 1);
    const float dx1 = (float)(W0 - 1) / (float)(W1 - 1);
    const float dy2 = (float)(H0 - 1) / (float)(H2 - 1);
    const float dx2 = (float)(W0 - 1) / (float)(W2 - 1);

    float* ws = (float*)d_ws;
    float* m12 = ws;
    float* m21 = m12 + (size_t)Bn * HW0;
    int*   cnt = (int*)(m21 + (size_t)Bn * HW0);
    float* list = (float*)(cnt + 16);

    float* l1 = out;
    float* l2 = l1 + (size_t)Bn * 70 * HW0;
    float* l3 = l2 + (size_t)Bn * 128 * (H1 * W1);

    hipMemsetAsync(cnt, 0, 16 * sizeof(int), stream);

    metric_kernel<<<nblk((long long)Bn * HW0), 256, 0, stream>>>(img1, img2, fl12, m12);
    metric_kernel<<<nblk((long long)Bn * HW0), 256, 0, stream>>>(img2, img1, fl21, m21);

    // grids (all divisible by 8 for the XCD swizzle)
    const int G0 = Bn * (H0 / 16) * (W0 / 16);   // 1792
    const int G1 = Bn * (H1 / 8) * (W1 / 16);    // 896
    const int G2 = Bn * (H2 / 8) * (W2 / 16);    // 224
    const int C0 = Bn * H0 * W0 / 256, C1 = Bn * H1 * W1 / 256, C2 = Bn * H2 * W2 / 256;

    // ---- level 0 (D=16, tile 16x16, 512-thread blocks, queue 4096) ----
    cleanup_kernel<0, 35, 16><<<C0, 256, 0, stream>>>(img1, f1_1, fl12, m12, alpha,
                                                      cnt + 0, list, H0, W0, 0.f, 0.f, 0.f);
    splat_tile<0, 35, 16, 16, 16, 512, 4096><<<G0, 512, 0, stream>>>(img1, f1_1, fl12, m12, alpha,
                                                                     cnt + 0, list, l1, 70, 0, H0, W0, 0.f, 0.f, 0.f);
    cleanup_kernel<0, 35, 16><<<C0, 256, 0, stream>>>(img2, f2_1, fl21, m21, alpha,
                                                      cnt + 1, list, H0, W0, 0.f, 0.f, 0.f);
    splat_tile<0, 35, 16, 16, 16, 512, 4096><<<G0, 512, 0, stream>>>(img2, f2_1, fl21, m21, alpha,
                                                                     cnt + 1, list, l1, 70, 35, H0, W0, 0.f, 0.f, 0.f);
    // ---- level 1 (D=8, tile 8x16, queue 2048) ----
    cleanup_kernel<1, 64, 8><<<C1, 256, 0, stream>>>(nullptr, f1_2, fl12, m12, alpha,
                                                     cnt + 2, list, H1, W1, 0.25f, dy1, dx1);
    splat_tile<1, 64, 8, 16, 8, 256, 2048><<<G1, 256, 0, stream>>>(nullptr, f1_2, fl12, m12, alpha,
                                                                   cnt + 2, list, l2, 128, 0, H1, W1, 0.25f, dy1, dx1);
    cleanup_kernel<1, 64, 8><<<C1, 256, 0, stream>>>(nullptr, f2_2, fl21, m21, alpha,
                                                     cnt + 3, list, H1, W1, 0.25f, dy1, dx1);
    splat_tile<1, 64, 8, 16, 8, 256, 2048><<<G1, 256, 0, stream>>>(nullptr, f2_2, fl21, m21, alpha,
                                                                   cnt + 3, list, l2, 128, 64, H1, W1, 0.25f, dy1, dx1);
    // ---- level 2 (D=8, tile 8x16, queue 2048) ----
    cleanup_kernel<1, 96, 8><<<C2, 256, 0, stream>>>(nullptr, f1_3, fl12, m12, alpha,
                                                     cnt + 4, list, H2, W2, 0.125f, dy2, dx2);
    splat_tile<1, 96, 8, 16, 8, 256, 2048><<<G2, 256, 0, stream>>>(nullptr, f1_3, fl12, m12, alpha,
                                                                   cnt + 4, list, l3, 192, 0, H2, W2, 0.125f, dy2, dx2);
    cleanup_kernel<1, 96, 8><<<C2, 256, 0, stream>>>(nullptr, f2_3, fl21, m21, alpha,
                                                     cnt + 5, list, H2, W2, 0.125f, dy2, dx2);
    splat_tile<1, 96, 8, 16, 8, 256, 2048><<<G2, 256, 0, stream>>>(nullptr, f2_3, fl21, m21, alpha,
                                                                   cnt + 5, list, l3, 192, 96, H2, W2, 0.125f, dy2, dx2);
}

// Round 12
// 1318.583 us; speedup vs baseline: 1.1986x; 1.1986x over previous
//
#include <hip/hip_runtime.h>
#include <math.h>

namespace {

constexpr int Bn = 4;
constexpr int H0 = 256, W0 = 448;
constexpr int H1 = 128, W1 = 224;
constexpr int H2 = 64,  W2 = 112;
constexpr int HW0 = H0 * W0;
constexpr int CAP = 8192;        // cleanup-list capacity

// np.linspace(-1+1/n, 1-1/n, n, dtype=f32) bit path (backwarp side; validated).
__device__ inline float lin_ac_f32(int i, int n) {
    if (i == n - 1) return (float)(1.0 - 1.0 / (double)n);
    double start = -1.0 + 1.0 / (double)n;
    double step  = (2.0 - 2.0 / (double)n) / (double)(n - 1);
    return (float)(start + (double)i * step);
}

// ---------------------------------------------------------------------------
// Backwarp + L1 occlusion metric (validated, unchanged).
// ---------------------------------------------------------------------------
__global__ void metric_kernel(const float* __restrict__ imgA,
                              const float* __restrict__ imgB,
                              const float* __restrict__ flow,
                              float* __restrict__ mout) {
    int idx = blockIdx.x * blockDim.x + threadIdx.x;
    int total = Bn * HW0;
    if (idx >= total) return;
    int x = idx % W0;
    int y = (idx / W0) % H0;
    int b = idx / HW0;

    const float* fb = flow + (size_t)b * 2 * HW0;
    float fx = fb[y * W0 + x];
    float fy = fb[(size_t)HW0 + y * W0 + x];

    const float sxc = (float)(2.0 / (double)(W0 - 1));
    const float syc = (float)(2.0 / (double)(H0 - 1));
    float gx = __fadd_rn(lin_ac_f32(x, W0), __fmul_rn(fx, sxc));
    float gy = __fadd_rn(lin_ac_f32(y, H0), __fmul_rn(fy, syc));
    float px = __fmul_rn(__fmul_rn(__fadd_rn(gx, 1.0f), 0.5f), (float)(W0 - 1));
    float py = __fmul_rn(__fmul_rn(__fadd_rn(gy, 1.0f), 0.5f), (float)(H0 - 1));

    float x0f = floorf(px), y0f = floorf(py);
    float x1f = x0f + 1.0f, y1f = y0f + 1.0f;
    int x0 = (int)x0f, y0 = (int)y0f, x1 = (int)x1f, y1 = (int)y1f;

    float tw[4] = { (x1f - px) * (y1f - py), (px - x0f) * (y1f - py),
                    (x1f - px) * (py - y0f), (px - x0f) * (py - y0f) };
    int tx[4] = { x0, x1, x0, x1 };
    int ty[4] = { y0, y0, y1, y1 };

    const float* ib = imgB + (size_t)b * 3 * HW0;
    float acc0 = 0.f, acc1 = 0.f, acc2 = 0.f;
#pragma unroll
    for (int t = 0; t < 4; ++t) {
        bool valid = (tx[t] >= 0) && (tx[t] < W0) && (ty[t] >= 0) && (ty[t] < H0);
        int xc = min(max(tx[t], 0), W0 - 1);
        int yc = min(max(ty[t], 0), H0 - 1);
        float ww = valid ? tw[t] : 0.f;
        int off = yc * W0 + xc;
        acc0 += ib[off] * ww;
        acc1 += ib[(size_t)HW0 + off] * ww;
        acc2 += ib[(size_t)2 * HW0 + off] * ww;
    }
    const float* ia = imgA + (size_t)b * 3 * HW0;
    int off = y * W0 + x;
    float m = (fabsf(ia[off] - acc0) +
               fabsf(ia[(size_t)HW0 + off] - acc1) +
               fabsf(ia[(size_t)2 * HW0 + off] - acc2)) * (1.f / 3.f);
    mout[idx] = m;
}

// jax-f32 linspace bit path + endpoint forcing (validated round 6).
__device__ inline void ac32_iota(int i, int n_in, int n_out, float delta,
                                 int& i0, int& i1, float& fr) {
    float v = (i == n_out - 1) ? (float)(n_in - 1) : __fmul_rn(delta, (float)i);
    float f0 = floorf(v);
    i0 = (int)f0;
    i1 = min(i0 + 1, n_in - 1);
    fr = __fsub_rn(v, f0);
}

// Unfused pinned f32 bilinear (validated round 6).
__device__ inline float bilerp32(const float* __restrict__ s, int Win,
                                 int y0, int y1, int x0, int x1,
                                 float wy, float wx) {
    float a = s[y0 * Win + x0], b = s[y1 * Win + x0];
    float c = s[y0 * Win + x1], d = s[y1 * Win + x1];
    float omwy = __fsub_rn(1.0f, wy), omwx = __fsub_rn(1.0f, wx);
    float r0 = __fadd_rn(__fmul_rn(a, omwy), __fmul_rn(b, wy));
    float r1 = __fadd_rn(__fmul_rn(c, omwy), __fmul_rn(d, wy));
    return __fadd_rn(__fmul_rn(r0, omwx), __fmul_rn(r1, wx));
}

// chunked XCD swizzle (grid divisible by 8)
__device__ inline int swz_block(int bid, int nblk) {
    int cpx = nblk >> 3;
    return (bid & 7) * cpx + (bid >> 3);
}

// ---------------------------------------------------------------------------
// Shared tap geometry — EXACT round-6 bit paths (validated).
// ---------------------------------------------------------------------------
template<int LVL, int D>
struct Geo {
    int   tx[4], ty[4];
    float tw[4];
    bool  reg;
    int   ry0, ry1, rx0, rx1;
    float wy, wx;
};

template<int LVL, int D>
__device__ inline Geo<LVL, D> geom(int x, int y, int b, int h, int w,
                                   const float* __restrict__ flow,
                                   float scale, float dly, float dlx) {
    Geo<LVL, D> g;
    float gx, gy, x0f, y0f, x1f, y1f;
    if constexpr (LVL == 0) {
        const float* fb = flow + (size_t)b * 2 * HW0;
        float fx = 0.5f * fb[y * W0 + x];
        float fy = 0.5f * fb[(size_t)HW0 + y * W0 + x];
        gx = (float)x + fx;
        gy = (float)y + fy;
        x0f = floorf(gx); y0f = floorf(gy);
        x1f = x0f + 1.f;  y1f = y0f + 1.f;
        g.tw[0] = (x1f - gx) * (y1f - gy); g.tw[1] = (gx - x0f) * (y1f - gy);
        g.tw[2] = (x1f - gx) * (gy - y0f); g.tw[3] = (gx - x0f) * (gy - y0f);
    } else {
        ac32_iota(y, H0, h, dly, g.ry0, g.ry1, g.wy);
        ac32_iota(x, W0, w, dlx, g.rx0, g.rx1, g.wx);
        const float* fB = flow + (size_t)b * 2 * HW0;
        float fx = __fmul_rn(bilerp32(fB, W0, g.ry0, g.ry1, g.rx0, g.rx1, g.wy, g.wx), scale);
        float fy = __fmul_rn(bilerp32(fB + (size_t)HW0, W0, g.ry0, g.ry1, g.rx0, g.rx1, g.wy, g.wx), scale);
        gx = __fadd_rn((float)x, fx);
        gy = __fadd_rn((float)y, fy);
        x0f = floorf(gx); y0f = floorf(gy);
        x1f = __fadd_rn(x0f, 1.0f); y1f = __fadd_rn(y0f, 1.0f);
        float dx0 = __fsub_rn(x1f, gx), dx1 = __fsub_rn(gx, x0f);
        float dy0 = __fsub_rn(y1f, gy), dy1 = __fsub_rn(gy, y0f);
        g.tw[0] = __fmul_rn(dx0, dy0); g.tw[1] = __fmul_rn(dx1, dy0);
        g.tw[2] = __fmul_rn(dx0, dy1); g.tw[3] = __fmul_rn(dx1, dy1);
    }
    int x0 = (int)x0f, y0 = (int)y0f;
    g.tx[0] = x0;     g.tx[1] = x0 + 1; g.tx[2] = x0;     g.tx[3] = x0 + 1;
    g.ty[0] = y0;     g.ty[1] = y0;     g.ty[2] = y0 + 1; g.ty[3] = y0 + 1;
    g.reg = (x0 >= x - D) && (x0 + 1 <= x + D) && (y0 >= y - D) && (y0 + 1 <= y + D);
    return g;
}

// ---------------------------------------------------------------------------
// Cleanup: irregular (|disp|>D) sources -> compact global list.
// ---------------------------------------------------------------------------
template<int LVL, int CB, int D>
__global__ __launch_bounds__(256) void cleanup_kernel(
        const float* __restrict__ img, const float* __restrict__ feat,
        const float* __restrict__ flow, const float* __restrict__ met,
        const float* __restrict__ alphap,
        int* __restrict__ cnt, float* __restrict__ list,
        int h, int w, float scale, float dly, float dlx) {
    int idx = blockIdx.x * 256 + threadIdx.x;
    int hw = h * w;
    if (idx >= Bn * hw) return;
    int x = idx % w, y = (idx / w) % h, b = idx / hw;

    Geo<LVL, D> g = geom<LVL, D>(x, y, b, h, w, flow, scale, dly, dlx);
    if (g.reg) return;

    float a = alphap[0];
    float wgt;
    if constexpr (LVL == 0) wgt = expf(a * met[(size_t)b * HW0 + y * W0 + x]);
    else {
        float m = bilerp32(met + (size_t)b * HW0, W0, g.ry0, g.ry1, g.rx0, g.rx1, g.wy, g.wx);
        wgt = expf(__fmul_rn(a, m));
    }
    int sidx = y * w + x;
#pragma unroll
    for (int t = 0; t < 4; ++t) {
        bool valid = (g.tx[t] >= 0) && (g.tx[t] < w) && (g.ty[t] >= 0) && (g.ty[t] < h);
        if (!valid) continue;
        int pos = atomicAdd(cnt, 1);
        if (pos >= CAP) continue;
        float* en = list + (size_t)pos * (CB + 2);
        en[0] = __int_as_float(b * hw + g.ty[t] * w + g.tx[t]);
        if constexpr (LVL == 0) {
            float twv = g.tw[t] * wgt;
            en[1] = twv;
            for (int c = 0; c < CB; ++c) {
                float v = (c < 3) ? img[((size_t)b * 3 + c) * hw + sidx]
                                  : feat[((size_t)b * 32 + (c - 3)) * hw + sidx];
                en[2 + c] = v * twv;
            }
        } else {
            en[1] = __fmul_rn(wgt, g.tw[t]);
            for (int c = 0; c < CB; ++c) {
                float v = feat[((size_t)b * CB + c) * hw + sidx];
                en[2 + c] = __fmul_rn(__fmul_rn(v, wgt), g.tw[t]);
            }
        }
    }
}

// ---------------------------------------------------------------------------
// Tile-owned splat (R10 structure). Change vs R10: the value-channel loop is
// CHUNKED — 32 channels preloaded into registers (unrolled, static indices),
// ONE vmcnt wait, then 128 independent ds_adds. Breaks the per-channel
// load->wait->atomic dependent chain (the round-10/11 latency floor:
// VGPR=52 showed the compiler kept the rolled loop, exposing full L2/HBM
// latency 35x per hit-iteration).
// ---------------------------------------------------------------------------
template<int LVL, int CB, int TH, int TW, int D, int NT>
__global__ __launch_bounds__(NT) void splat_tile(
        const float* __restrict__ img, const float* __restrict__ feat,
        const float* __restrict__ flow, const float* __restrict__ met,
        const float* __restrict__ alphap,
        const int* __restrict__ cnt, const float* __restrict__ list,
        float* __restrict__ outp, int Cout, int cbase,
        int h, int w, float scale, float dly, float dlx) {
    constexpr int CV = CB + 1;
    constexpr int TPIX = TH * TW;
    constexpr int CHUNK = 32;
    __shared__ float tile[CV * TPIX];

    const int hw = h * w;
    const int tilesX = w / TW, tilesY = h / TH;
    int s = swz_block(blockIdx.x, gridDim.x);
    int tpb = tilesX * tilesY;
    int b = s / tpb, r = s % tpb;
    int ty0 = (r / tilesX) * TH, tx0 = (r % tilesX) * TW;
    int tid = threadIdx.x;

    for (int i = tid; i < CV * TPIX; i += NT) tile[i] = 0.f;
    __syncthreads();

    float a = alphap[0];
    const int Wh = TH + 2 * D, Ww = TW + 2 * D;
    const int wy0 = ty0 - D, wx0 = tx0 - D;

    for (int i = tid; i < Wh * Ww; i += NT) {
        int sy = wy0 + i / Ww, sx = wx0 + i % Ww;
        if (sy < 0 || sy >= h || sx < 0 || sx >= w) continue;

        Geo<LVL, D> g = geom<LVL, D>(sx, sy, b, h, w, flow, scale, dly, dlx);

        int lidx[4]; int nact = 0;
#pragma unroll
        for (int t = 0; t < 4; ++t) {
            bool in = g.reg && g.tx[t] >= tx0 && g.tx[t] < tx0 + TW &&
                      g.ty[t] >= ty0 && g.ty[t] < ty0 + TH;
            lidx[t] = in ? ((g.ty[t] - ty0) * TW + (g.tx[t] - tx0)) : -1;
            nact += in;
        }
        if (!nact) continue;

        float wgt;
        if constexpr (LVL == 0) wgt = expf(a * met[(size_t)b * HW0 + sy * W0 + sx]);
        else {
            float m = bilerp32(met + (size_t)b * HW0, W0, g.ry0, g.ry1, g.rx0, g.rx1, g.wy, g.wx);
            wgt = expf(__fmul_rn(a, m));
        }

        float twv[4];
#pragma unroll
        for (int t = 0; t < 4; ++t)
            twv[t] = (LVL == 0) ? g.tw[t] * wgt : __fmul_rn(wgt, g.tw[t]);

#pragma unroll
        for (int t = 0; t < 4; ++t)
            if (lidx[t] >= 0) atomicAdd(&tile[CB * TPIX + lidx[t]], twv[t]);

        int sidx = sy * w + sx;
        // ---- chunked preload: batch loads, single wait, batch atomics ----
        for (int c0 = 0; c0 < CB; c0 += CHUNK) {
            float v[CHUNK];
#pragma unroll
            for (int cc = 0; cc < CHUNK; ++cc) {
                int c = c0 + cc;
                if (c < CB) {
                    if constexpr (LVL == 0)
                        v[cc] = (c < 3) ? img[((size_t)b * 3 + c) * hw + sidx]
                                        : feat[((size_t)b * 32 + (c - 3)) * hw + sidx];
                    else
                        v[cc] = feat[((size_t)b * CB + c) * hw + sidx];
                }
            }
#pragma unroll
            for (int cc = 0; cc < CHUNK; ++cc) {
                int c = c0 + cc;
                if (c >= CB) continue;
                float* tp = &tile[c * TPIX];
#pragma unroll
                for (int t = 0; t < 4; ++t) {
                    if (lidx[t] < 0) continue;
                    float add;
                    if constexpr (LVL == 0) add = v[cc] * twv[t];
                    else add = __fmul_rn(__fmul_rn(v[cc], wgt), g.tw[t]);
                    atomicAdd(&tp[lidx[t]], add);
                }
            }
        }
    }
    __syncthreads();

    // merge cleanup entries (uniform small count)
    int n = min(cnt[0], CAP);
    if (n > 0) {
        for (int e = tid; e < n; e += NT) {
            const float* en = list + (size_t)e * (CB + 2);
            int tgt = __float_as_int(en[0]);
            int eb = tgt / hw, ep = tgt % hw;
            int py = ep / w, px = ep % w;
            if (eb == b && py >= ty0 && py < ty0 + TH && px >= tx0 && px < tx0 + TW) {
                int l = (py - ty0) * TW + (px - tx0);
                atomicAdd(&tile[CB * TPIX + l], en[1]);
                for (int c = 0; c < CB; ++c) atomicAdd(&tile[c * TPIX + l], en[2 + c]);
            }
        }
        __syncthreads();
    }

    // normalize + store NCHW
    for (int p = tid; p < TPIX; p += NT) {
        float denom = tile[CB * TPIX + p] + 1e-7f;
        int gp = (ty0 + p / TW) * w + (tx0 + p % TW);
        float* ob = outp + ((size_t)b * Cout + cbase) * hw + gp;
        for (int c = 0; c < CB; ++c)
            ob[(size_t)c * hw] = tile[c * TPIX + p] / denom;
    }
}

inline int nblk(long long n) { return (int)((n + 255) / 256); }

} // namespace

extern "C" void kernel_launch(void* const* d_in, const int* in_sizes, int n_in,
                              void* d_out, int out_size, void* d_ws, size_t ws_size,
                              hipStream_t stream) {
    const float* img1 = (const float*)d_in[0];
    const float* img2 = (const float*)d_in[1];
    const float* f1_1 = (const float*)d_in[2];
    const float* f1_2 = (const float*)d_in[3];
    const float* f1_3 = (const float*)d_in[4];
    const float* f2_1 = (const float*)d_in[5];
    const float* f2_2 = (const float*)d_in[6];
    const float* f2_3 = (const float*)d_in[7];
    const float* fl12 = (const float*)d_in[8];
    const float* fl21 = (const float*)d_in[9];
    const float* alpha = (const float*)d_in[10];
    float* out = (float*)d_out;

    const float dy1 = (float)(H0 - 1) / (float)(H1 - 1);
    const float dx1 = (float)(W0 - 1) / (float)(W1 - 1);
    const float dy2 = (float)(H0 - 1) / (float)(H2 - 1);
    const float dx2 = (float)(W0 - 1) / (float)(W2 - 1);

    float* ws = (float*)d_ws;
    float* m12 = ws;
    float* m21 = m12 + (size_t)Bn * HW0;
    int*   cnt = (int*)(m21 + (size_t)Bn * HW0);
    float* list = (float*)(cnt + 16);

    float* l1 = out;
    float* l2 = l1 + (size_t)Bn * 70 * HW0;
    float* l3 = l2 + (size_t)Bn * 128 * (H1 * W1);

    hipMemsetAsync(cnt, 0, 16 * sizeof(int), stream);

    metric_kernel<<<nblk((long long)Bn * HW0), 256, 0, stream>>>(img1, img2, fl12, m12);
    metric_kernel<<<nblk((long long)Bn * HW0), 256, 0, stream>>>(img2, img1, fl21, m21);

    // grids (all divisible by 8 for the XCD swizzle)
    const int G0 = Bn * (H0 / 16) * (W0 / 28);   // 1024
    const int G1 = Bn * (H1 / 8) * (W1 / 16);    // 896
    const int G2 = Bn * (H2 / 8) * (W2 / 16);    // 224
    const int C0 = Bn * H0 * W0 / 256, C1 = Bn * H1 * W1 / 256, C2 = Bn * H2 * W2 / 256;

    // ---- level 0 (D=16, tile 16x28, 512-thread blocks) ----
    cleanup_kernel<0, 35, 16><<<C0, 256, 0, stream>>>(img1, f1_1, fl12, m12, alpha,
                                                      cnt + 0, list, H0, W0, 0.f, 0.f, 0.f);
    splat_tile<0, 35, 16, 28, 16, 512><<<G0, 512, 0, stream>>>(img1, f1_1, fl12, m12, alpha,
                                                               cnt + 0, list, l1, 70, 0, H0, W0, 0.f, 0.f, 0.f);
    cleanup_kernel<0, 35, 16><<<C0, 256, 0, stream>>>(img2, f2_1, fl21, m21, alpha,
                                                      cnt + 1, list, H0, W0, 0.f, 0.f, 0.f);
    splat_tile<0, 35, 16, 28, 16, 512><<<G0, 512, 0, stream>>>(img2, f2_1, fl21, m21, alpha,
                                                               cnt + 1, list, l1, 70, 35, H0, W0, 0.f, 0.f, 0.f);
    // ---- level 1 (D=8) ----
    cleanup_kernel<1, 64, 8><<<C1, 256, 0, stream>>>(nullptr, f1_2, fl12, m12, alpha,
                                                     cnt + 2, list, H1, W1, 0.25f, dy1, dx1);
    splat_tile<1, 64, 8, 16, 8, 256><<<G1, 256, 0, stream>>>(nullptr, f1_2, fl12, m12, alpha,
                                                             cnt + 2, list, l2, 128, 0, H1, W1, 0.25f, dy1, dx1);
    cleanup_kernel<1, 64, 8><<<C1, 256, 0, stream>>>(nullptr, f2_2, fl21, m21, alpha,
                                                     cnt + 3, list, H1, W1, 0.25f, dy1, dx1);
    splat_tile<1, 64, 8, 16, 8, 256><<<G1, 256, 0, stream>>>(nullptr, f2_2, fl21, m21, alpha,
                                                             cnt + 3, list, l2, 128, 64, H1, W1, 0.25f, dy1, dx1);
    // ---- level 2 (D=8) ----
    cleanup_kernel<1, 96, 8><<<C2, 256, 0, stream>>>(nullptr, f1_3, fl12, m12, alpha,
                                                     cnt + 4, list, H2, W2, 0.125f, dy2, dx2);
    splat_tile<1, 96, 8, 16, 8, 256><<<G2, 256, 0, stream>>>(nullptr, f1_3, fl12, m12, alpha,
                                                             cnt + 4, list, l3, 192, 0, H2, W2, 0.125f, dy2, dx2);
    cleanup_kernel<1, 96, 8><<<C2, 256, 0, stream>>>(nullptr, f2_3, fl21, m21, alpha,
                                                     cnt + 5, list, H2, W2, 0.125f, dy2, dx2);
    splat_tile<1, 96, 8, 16, 8, 256><<<G2, 256, 0, stream>>>(nullptr, f2_3, fl21, m21, alpha,
                                                             cnt + 5, list, l3, 192, 96, H2, W2, 0.125f, dy2, dx2);
}

// Round 13
// 1311.076 us; speedup vs baseline: 1.2054x; 1.0057x over previous
//
#include <hip/hip_runtime.h>
#include <math.h>

namespace {

constexpr int Bn = 4;
constexpr int H0 = 256, W0 = 448;
constexpr int H1 = 128, W1 = 224;
constexpr int H2 = 64,  W2 = 112;
constexpr int HW0 = H0 * W0;
constexpr int CAP = 8192;        // cleanup-list capacity

// np.linspace(-1+1/n, 1-1/n, n, dtype=f32) bit path (backwarp side; validated).
__device__ inline float lin_ac_f32(int i, int n) {
    if (i == n - 1) return (float)(1.0 - 1.0 / (double)n);
    double start = -1.0 + 1.0 / (double)n;
    double step  = (2.0 - 2.0 / (double)n) / (double)(n - 1);
    return (float)(start + (double)i * step);
}

// ---------------------------------------------------------------------------
// Backwarp + L1 occlusion metric (validated, unchanged).
// ---------------------------------------------------------------------------
__global__ void metric_kernel(const float* __restrict__ imgA,
                              const float* __restrict__ imgB,
                              const float* __restrict__ flow,
                              float* __restrict__ mout) {
    int idx = blockIdx.x * blockDim.x + threadIdx.x;
    int total = Bn * HW0;
    if (idx >= total) return;
    int x = idx % W0;
    int y = (idx / W0) % H0;
    int b = idx / HW0;

    const float* fb = flow + (size_t)b * 2 * HW0;
    float fx = fb[y * W0 + x];
    float fy = fb[(size_t)HW0 + y * W0 + x];

    const float sxc = (float)(2.0 / (double)(W0 - 1));
    const float syc = (float)(2.0 / (double)(H0 - 1));
    float gx = __fadd_rn(lin_ac_f32(x, W0), __fmul_rn(fx, sxc));
    float gy = __fadd_rn(lin_ac_f32(y, H0), __fmul_rn(fy, syc));
    float px = __fmul_rn(__fmul_rn(__fadd_rn(gx, 1.0f), 0.5f), (float)(W0 - 1));
    float py = __fmul_rn(__fmul_rn(__fadd_rn(gy, 1.0f), 0.5f), (float)(H0 - 1));

    float x0f = floorf(px), y0f = floorf(py);
    float x1f = x0f + 1.0f, y1f = y0f + 1.0f;
    int x0 = (int)x0f, y0 = (int)y0f, x1 = (int)x1f, y1 = (int)y1f;

    float tw[4] = { (x1f - px) * (y1f - py), (px - x0f) * (y1f - py),
                    (x1f - px) * (py - y0f), (px - x0f) * (py - y0f) };
    int tx[4] = { x0, x1, x0, x1 };
    int ty[4] = { y0, y0, y1, y1 };

    const float* ib = imgB + (size_t)b * 3 * HW0;
    float acc0 = 0.f, acc1 = 0.f, acc2 = 0.f;
#pragma unroll
    for (int t = 0; t < 4; ++t) {
        bool valid = (tx[t] >= 0) && (tx[t] < W0) && (ty[t] >= 0) && (ty[t] < H0);
        int xc = min(max(tx[t], 0), W0 - 1);
        int yc = min(max(ty[t], 0), H0 - 1);
        float ww = valid ? tw[t] : 0.f;
        int off = yc * W0 + xc;
        acc0 += ib[off] * ww;
        acc1 += ib[(size_t)HW0 + off] * ww;
        acc2 += ib[(size_t)2 * HW0 + off] * ww;
    }
    const float* ia = imgA + (size_t)b * 3 * HW0;
    int off = y * W0 + x;
    float m = (fabsf(ia[off] - acc0) +
               fabsf(ia[(size_t)HW0 + off] - acc1) +
               fabsf(ia[(size_t)2 * HW0 + off] - acc2)) * (1.f / 3.f);
    mout[idx] = m;
}

// jax-f32 linspace bit path + endpoint forcing (validated round 6).
__device__ inline void ac32_iota(int i, int n_in, int n_out, float delta,
                                 int& i0, int& i1, float& fr) {
    float v = (i == n_out - 1) ? (float)(n_in - 1) : __fmul_rn(delta, (float)i);
    float f0 = floorf(v);
    i0 = (int)f0;
    i1 = min(i0 + 1, n_in - 1);
    fr = __fsub_rn(v, f0);
}

// Unfused pinned f32 bilinear (validated round 6).
__device__ inline float bilerp32(const float* __restrict__ s, int Win,
                                 int y0, int y1, int x0, int x1,
                                 float wy, float wx) {
    float a = s[y0 * Win + x0], b = s[y1 * Win + x0];
    float c = s[y0 * Win + x1], d = s[y1 * Win + x1];
    float omwy = __fsub_rn(1.0f, wy), omwx = __fsub_rn(1.0f, wx);
    float r0 = __fadd_rn(__fmul_rn(a, omwy), __fmul_rn(b, wy));
    float r1 = __fadd_rn(__fmul_rn(c, omwy), __fmul_rn(d, wy));
    return __fadd_rn(__fmul_rn(r0, omwx), __fmul_rn(r1, wx));
}

// chunked XCD swizzle (grid divisible by 8)
__device__ inline int swz_block(int bid, int nblk) {
    int cpx = nblk >> 3;
    return (bid & 7) * cpx + (bid >> 3);
}

// ---------------------------------------------------------------------------
// Shared tap geometry — EXACT round-6 bit paths (validated).
// ---------------------------------------------------------------------------
template<int LVL, int D>
struct Geo {
    int   tx[4], ty[4];
    float tw[4];
    bool  reg;
    int   ry0, ry1, rx0, rx1;
    float wy, wx;
};

template<int LVL, int D>
__device__ inline Geo<LVL, D> geom(int x, int y, int b, int h, int w,
                                   const float* __restrict__ flow,
                                   float scale, float dly, float dlx) {
    Geo<LVL, D> g;
    float gx, gy, x0f, y0f, x1f, y1f;
    if constexpr (LVL == 0) {
        const float* fb = flow + (size_t)b * 2 * HW0;
        float fx = 0.5f * fb[y * W0 + x];
        float fy = 0.5f * fb[(size_t)HW0 + y * W0 + x];
        gx = (float)x + fx;
        gy = (float)y + fy;
        x0f = floorf(gx); y0f = floorf(gy);
        x1f = x0f + 1.f;  y1f = y0f + 1.f;
        g.tw[0] = (x1f - gx) * (y1f - gy); g.tw[1] = (gx - x0f) * (y1f - gy);
        g.tw[2] = (x1f - gx) * (gy - y0f); g.tw[3] = (gx - x0f) * (gy - y0f);
    } else {
        ac32_iota(y, H0, h, dly, g.ry0, g.ry1, g.wy);
        ac32_iota(x, W0, w, dlx, g.rx0, g.rx1, g.wx);
        const float* fB = flow + (size_t)b * 2 * HW0;
        float fx = __fmul_rn(bilerp32(fB, W0, g.ry0, g.ry1, g.rx0, g.rx1, g.wy, g.wx), scale);
        float fy = __fmul_rn(bilerp32(fB + (size_t)HW0, W0, g.ry0, g.ry1, g.rx0, g.rx1, g.wy, g.wx), scale);
        gx = __fadd_rn((float)x, fx);
        gy = __fadd_rn((float)y, fy);
        x0f = floorf(gx); y0f = floorf(gy);
        x1f = __fadd_rn(x0f, 1.0f); y1f = __fadd_rn(y0f, 1.0f);
        float dx0 = __fsub_rn(x1f, gx), dx1 = __fsub_rn(gx, x0f);
        float dy0 = __fsub_rn(y1f, gy), dy1 = __fsub_rn(gy, y0f);
        g.tw[0] = __fmul_rn(dx0, dy0); g.tw[1] = __fmul_rn(dx1, dy0);
        g.tw[2] = __fmul_rn(dx0, dy1); g.tw[3] = __fmul_rn(dx1, dy1);
    }
    int x0 = (int)x0f, y0 = (int)y0f;
    g.tx[0] = x0;     g.tx[1] = x0 + 1; g.tx[2] = x0;     g.tx[3] = x0 + 1;
    g.ty[0] = y0;     g.ty[1] = y0;     g.ty[2] = y0 + 1; g.ty[3] = y0 + 1;
    g.reg = (x0 >= x - D) && (x0 + 1 <= x + D) && (y0 >= y - D) && (y0 + 1 <= y + D);
    return g;
}

// ---------------------------------------------------------------------------
// Cleanup: irregular (|disp|>D) sources -> compact global list.
// ---------------------------------------------------------------------------
template<int LVL, int CB, int D>
__global__ __launch_bounds__(256) void cleanup_kernel(
        const float* __restrict__ img, const float* __restrict__ feat,
        const float* __restrict__ flow, const float* __restrict__ met,
        const float* __restrict__ alphap,
        int* __restrict__ cnt, float* __restrict__ list,
        int h, int w, float scale, float dly, float dlx) {
    int idx = blockIdx.x * 256 + threadIdx.x;
    int hw = h * w;
    if (idx >= Bn * hw) return;
    int x = idx % w, y = (idx / w) % h, b = idx / hw;

    Geo<LVL, D> g = geom<LVL, D>(x, y, b, h, w, flow, scale, dly, dlx);
    if (g.reg) return;

    float a = alphap[0];
    float wgt;
    if constexpr (LVL == 0) wgt = expf(a * met[(size_t)b * HW0 + y * W0 + x]);
    else {
        float m = bilerp32(met + (size_t)b * HW0, W0, g.ry0, g.ry1, g.rx0, g.rx1, g.wy, g.wx);
        wgt = expf(__fmul_rn(a, m));
    }
    int sidx = y * w + x;
#pragma unroll
    for (int t = 0; t < 4; ++t) {
        bool valid = (g.tx[t] >= 0) && (g.tx[t] < w) && (g.ty[t] >= 0) && (g.ty[t] < h);
        if (!valid) continue;
        int pos = atomicAdd(cnt, 1);
        if (pos >= CAP) continue;
        float* en = list + (size_t)pos * (CB + 2);
        en[0] = __int_as_float(b * hw + g.ty[t] * w + g.tx[t]);
        if constexpr (LVL == 0) {
            float twv = g.tw[t] * wgt;
            en[1] = twv;
            for (int c = 0; c < CB; ++c) {
                float v = (c < 3) ? img[((size_t)b * 3 + c) * hw + sidx]
                                  : feat[((size_t)b * 32 + (c - 3)) * hw + sidx];
                en[2 + c] = v * twv;
            }
        } else {
            en[1] = __fmul_rn(wgt, g.tw[t]);
            for (int c = 0; c < CB; ++c) {
                float v = feat[((size_t)b * CB + c) * hw + sidx];
                en[2 + c] = __fmul_rn(__fmul_rn(v, wgt), g.tw[t]);
            }
        }
    }
}

// ---------------------------------------------------------------------------
// Tile-owned splat. Change vs R12: the CHUNK=16 register preload is ENFORCED
// with sched_barrier(0) between the load batch and the atomic batch (rule:
// hipcc sinks loads to uses otherwise — R12's VGPR=52 proved it), and
// __launch_bounds__ declares the LDS-limited occupancy so the VGPR cap
// rises to ~128/160 and the batch can stay resident.
// ---------------------------------------------------------------------------
template<int LVL, int CB, int TH, int TW, int D, int NT>
__global__ __launch_bounds__(NT, (NT == 512) ? 4 : 3) void splat_tile(
        const float* __restrict__ img, const float* __restrict__ feat,
        const float* __restrict__ flow, const float* __restrict__ met,
        const float* __restrict__ alphap,
        const int* __restrict__ cnt, const float* __restrict__ list,
        float* __restrict__ outp, int Cout, int cbase,
        int h, int w, float scale, float dly, float dlx) {
    constexpr int CV = CB + 1;
    constexpr int TPIX = TH * TW;
    constexpr int CHUNK = 16;
    __shared__ float tile[CV * TPIX];

    const int hw = h * w;
    const int tilesX = w / TW, tilesY = h / TH;
    int s = swz_block(blockIdx.x, gridDim.x);
    int tpb = tilesX * tilesY;
    int b = s / tpb, r = s % tpb;
    int ty0 = (r / tilesX) * TH, tx0 = (r % tilesX) * TW;
    int tid = threadIdx.x;

    for (int i = tid; i < CV * TPIX; i += NT) tile[i] = 0.f;
    __syncthreads();

    float a = alphap[0];
    const int Wh = TH + 2 * D, Ww = TW + 2 * D;
    const int wy0 = ty0 - D, wx0 = tx0 - D;

    for (int i = tid; i < Wh * Ww; i += NT) {
        int sy = wy0 + i / Ww, sx = wx0 + i % Ww;
        if (sy < 0 || sy >= h || sx < 0 || sx >= w) continue;

        Geo<LVL, D> g = geom<LVL, D>(sx, sy, b, h, w, flow, scale, dly, dlx);

        int lidx[4]; int nact = 0;
#pragma unroll
        for (int t = 0; t < 4; ++t) {
            bool in = g.reg && g.tx[t] >= tx0 && g.tx[t] < tx0 + TW &&
                      g.ty[t] >= ty0 && g.ty[t] < ty0 + TH;
            lidx[t] = in ? ((g.ty[t] - ty0) * TW + (g.tx[t] - tx0)) : -1;
            nact += in;
        }
        if (!nact) continue;

        float wgt;
        if constexpr (LVL == 0) wgt = expf(a * met[(size_t)b * HW0 + sy * W0 + sx]);
        else {
            float m = bilerp32(met + (size_t)b * HW0, W0, g.ry0, g.ry1, g.rx0, g.rx1, g.wy, g.wx);
            wgt = expf(__fmul_rn(a, m));
        }

        float twv[4];
#pragma unroll
        for (int t = 0; t < 4; ++t)
            twv[t] = (LVL == 0) ? g.tw[t] * wgt : __fmul_rn(wgt, g.tw[t]);

#pragma unroll
        for (int t = 0; t < 4; ++t)
            if (lidx[t] >= 0) atomicAdd(&tile[CB * TPIX + lidx[t]], twv[t]);

        int sidx = sy * w + sx;
        // ---- enforced chunked preload: batch loads | sched fence | atomics
#pragma unroll
        for (int c0 = 0; c0 < CB; c0 += CHUNK) {
            float v[CHUNK];
#pragma unroll
            for (int cc = 0; cc < CHUNK; ++cc) {
                int c = c0 + cc;
                if (c < CB) {
                    if constexpr (LVL == 0)
                        v[cc] = (c < 3) ? img[((size_t)b * 3 + c) * hw + sidx]
                                        : feat[((size_t)b * 32 + (c - 3)) * hw + sidx];
                    else
                        v[cc] = feat[((size_t)b * CB + c) * hw + sidx];
                }
            }
            __builtin_amdgcn_sched_barrier(0);   // pin: all CHUNK loads issue first
#pragma unroll
            for (int cc = 0; cc < CHUNK; ++cc) {
                int c = c0 + cc;
                if (c >= CB) continue;
                float* tp = &tile[c * TPIX];
#pragma unroll
                for (int t = 0; t < 4; ++t) {
                    if (lidx[t] < 0) continue;
                    float add;
                    if constexpr (LVL == 0) add = v[cc] * twv[t];
                    else add = __fmul_rn(__fmul_rn(v[cc], wgt), g.tw[t]);
                    atomicAdd(&tp[lidx[t]], add);
                }
            }
        }
    }
    __syncthreads();

    // merge cleanup entries (uniform small count)
    int n = min(cnt[0], CAP);
    if (n > 0) {
        for (int e = tid; e < n; e += NT) {
            const float* en = list + (size_t)e * (CB + 2);
            int tgt = __float_as_int(en[0]);
            int eb = tgt / hw, ep = tgt % hw;
            int py = ep / w, px = ep % w;
            if (eb == b && py >= ty0 && py < ty0 + TH && px >= tx0 && px < tx0 + TW) {
                int l = (py - ty0) * TW + (px - tx0);
                atomicAdd(&tile[CB * TPIX + l], en[1]);
                for (int c = 0; c < CB; ++c) atomicAdd(&tile[c * TPIX + l], en[2 + c]);
            }
        }
        __syncthreads();
    }

    // normalize + store NCHW
    for (int p = tid; p < TPIX; p += NT) {
        float denom = tile[CB * TPIX + p] + 1e-7f;
        int gp = (ty0 + p / TW) * w + (tx0 + p % TW);
        float* ob = outp + ((size_t)b * Cout + cbase) * hw + gp;
        for (int c = 0; c < CB; ++c)
            ob[(size_t)c * hw] = tile[c * TPIX + p] / denom;
    }
}

inline int nblk(long long n) { return (int)((n + 255) / 256); }

} // namespace

extern "C" void kernel_launch(void* const* d_in, const int* in_sizes, int n_in,
                              void* d_out, int out_size, void* d_ws, size_t ws_size,
                              hipStream_t stream) {
    const float* img1 = (const float*)d_in[0];
    const float* img2 = (const float*)d_in[1];
    const float* f1_1 = (const float*)d_in[2];
    const float* f1_2 = (const float*)d_in[3];
    const float* f1_3 = (const float*)d_in[4];
    const float* f2_1 = (const float*)d_in[5];
    const float* f2_2 = (const float*)d_in[6];
    const float* f2_3 = (const float*)d_in[7];
    const float* fl12 = (const float*)d_in[8];
    const float* fl21 = (const float*)d_in[9];
    const float* alpha = (const float*)d_in[10];
    float* out = (float*)d_out;

    const float dy1 = (float)(H0 - 1) / (float)(H1 - 1);
    const float dx1 = (float)(W0 - 1) / (float)(W1 - 1);
    const float dy2 = (float)(H0 - 1) / (float)(H2 - 1);
    const float dx2 = (float)(W0 - 1) / (float)(W2 - 1);

    float* ws = (float*)d_ws;
    float* m12 = ws;
    float* m21 = m12 + (size_t)Bn * HW0;
    int*   cnt = (int*)(m21 + (size_t)Bn * HW0);
    float* list = (float*)(cnt + 16);

    float* l1 = out;
    float* l2 = l1 + (size_t)Bn * 70 * HW0;
    float* l3 = l2 + (size_t)Bn * 128 * (H1 * W1);

    hipMemsetAsync(cnt, 0, 16 * sizeof(int), stream);

    metric_kernel<<<nblk((long long)Bn * HW0), 256, 0, stream>>>(img1, img2, fl12, m12);
    metric_kernel<<<nblk((long long)Bn * HW0), 256, 0, stream>>>(img2, img1, fl21, m21);

    // grids (all divisible by 8 for the XCD swizzle)
    const int G0 = Bn * (H0 / 16) * (W0 / 28);   // 1024
    const int G1 = Bn * (H1 / 8) * (W1 / 16);    // 896
    const int G2 = Bn * (H2 / 8) * (W2 / 16);    // 224
    const int C0 = Bn * H0 * W0 / 256, C1 = Bn * H1 * W1 / 256, C2 = Bn * H2 * W2 / 256;

    // ---- level 0 (D=16, tile 16x28, 512-thread blocks) ----
    cleanup_kernel<0, 35, 16><<<C0, 256, 0, stream>>>(img1, f1_1, fl12, m12, alpha,
                                                      cnt + 0, list, H0, W0, 0.f, 0.f, 0.f);
    splat_tile<0, 35, 16, 28, 16, 512><<<G0, 512, 0, stream>>>(img1, f1_1, fl12, m12, alpha,
                                                               cnt + 0, list, l1, 70, 0, H0, W0, 0.f, 0.f, 0.f);
    cleanup_kernel<0, 35, 16><<<C0, 256, 0, stream>>>(img2, f2_1, fl21, m21, alpha,
                                                      cnt + 1, list, H0, W0, 0.f, 0.f, 0.f);
    splat_tile<0, 35, 16, 28, 16, 512><<<G0, 512, 0, stream>>>(img2, f2_1, fl21, m21, alpha,
                                                               cnt + 1, list, l1, 70, 35, H0, W0, 0.f, 0.f, 0.f);
    // ---- level 1 (D=8) ----
    cleanup_kernel<1, 64, 8><<<C1, 256, 0, stream>>>(nullptr, f1_2, fl12, m12, alpha,
                                                     cnt + 2, list, H1, W1, 0.25f, dy1, dx1);
    splat_tile<1, 64, 8, 16, 8, 256><<<G1, 256, 0, stream>>>(nullptr, f1_2, fl12, m12, alpha,
                                                             cnt + 2, list, l2, 128, 0, H1, W1, 0.25f, dy1, dx1);
    cleanup_kernel<1, 64, 8><<<C1, 256, 0, stream>>>(nullptr, f2_2, fl21, m21, alpha,
                                                     cnt + 3, list, H1, W1, 0.25f, dy1, dx1);
    splat_tile<1, 64, 8, 16, 8, 256><<<G1, 256, 0, stream>>>(nullptr, f2_2, fl21, m21, alpha,
                                                             cnt + 3, list, l2, 128, 64, H1, W1, 0.25f, dy1, dx1);
    // ---- level 2 (D=8) ----
    cleanup_kernel<1, 96, 8><<<C2, 256, 0, stream>>>(nullptr, f1_3, fl12, m12, alpha,
                                                     cnt + 4, list, H2, W2, 0.125f, dy2, dx2);
    splat_tile<1, 96, 8, 16, 8, 256><<<G2, 256, 0, stream>>>(nullptr, f1_3, fl12, m12, alpha,
                                                             cnt + 4, list, l3, 192, 0, H2, W2, 0.125f, dy2, dx2);
    cleanup_kernel<1, 96, 8><<<C2, 256, 0, stream>>>(nullptr, f2_3, fl21, m21, alpha,
                                                     cnt + 5, list, H2, W2, 0.125f, dy2, dx2);
    splat_tile<1, 96, 8, 16, 8, 256><<<G2, 256, 0, stream>>>(nullptr, f2_3, fl21, m21, alpha,
                                                             cnt + 5, list, l3, 192, 96, H2, W2, 0.125f, dy2, dx2);
}

// Round 14
// 597.865 us; speedup vs baseline: 2.6434x; 2.1929x over previous
//
#include <hip/hip_runtime.h>
#include <math.h>

namespace {

constexpr int Bn = 4;
constexpr int H0 = 256, W0 = 448;
constexpr int H1 = 128, W1 = 224;
constexpr int H2 = 64,  W2 = 112;
constexpr int HW0 = H0 * W0;
constexpr int IRRCAP = 8192;
constexpr int OVCAP  = 4096;
constexpr int KB = 12;            // bin capacity (Poisson mean ~1, max ~13 over 1M cells)

// np.linspace(-1+1/n, 1-1/n, n, dtype=f32) bit path (backwarp side; validated).
__device__ inline float lin_ac_f32(int i, int n) {
    if (i == n - 1) return (float)(1.0 - 1.0 / (double)n);
    double start = -1.0 + 1.0 / (double)n;
    double step  = (2.0 - 2.0 / (double)n) / (double)(n - 1);
    return (float)(start + (double)i * step);
}

// ---------------------------------------------------------------------------
// Backwarp + L1 occlusion metric (validated, unchanged).
// ---------------------------------------------------------------------------
__global__ void metric_kernel(const float* __restrict__ imgA,
                              const float* __restrict__ imgB,
                              const float* __restrict__ flow,
                              float* __restrict__ mout) {
    int idx = blockIdx.x * blockDim.x + threadIdx.x;
    int total = Bn * HW0;
    if (idx >= total) return;
    int x = idx % W0;
    int y = (idx / W0) % H0;
    int b = idx / HW0;

    const float* fb = flow + (size_t)b * 2 * HW0;
    float fx = fb[y * W0 + x];
    float fy = fb[(size_t)HW0 + y * W0 + x];

    const float sxc = (float)(2.0 / (double)(W0 - 1));
    const float syc = (float)(2.0 / (double)(H0 - 1));
    float gx = __fadd_rn(lin_ac_f32(x, W0), __fmul_rn(fx, sxc));
    float gy = __fadd_rn(lin_ac_f32(y, H0), __fmul_rn(fy, syc));
    float px = __fmul_rn(__fmul_rn(__fadd_rn(gx, 1.0f), 0.5f), (float)(W0 - 1));
    float py = __fmul_rn(__fmul_rn(__fadd_rn(gy, 1.0f), 0.5f), (float)(H0 - 1));

    float x0f = floorf(px), y0f = floorf(py);
    float x1f = x0f + 1.0f, y1f = y0f + 1.0f;
    int x0 = (int)x0f, y0 = (int)y0f, x1 = (int)x1f, y1 = (int)y1f;

    float tw[4] = { (x1f - px) * (y1f - py), (px - x0f) * (y1f - py),
                    (x1f - px) * (py - y0f), (px - x0f) * (py - y0f) };
    int tx[4] = { x0, x1, x0, x1 };
    int ty[4] = { y0, y0, y1, y1 };

    const float* ib = imgB + (size_t)b * 3 * HW0;
    float acc0 = 0.f, acc1 = 0.f, acc2 = 0.f;
#pragma unroll
    for (int t = 0; t < 4; ++t) {
        bool valid = (tx[t] >= 0) && (tx[t] < W0) && (ty[t] >= 0) && (ty[t] < H0);
        int xc = min(max(tx[t], 0), W0 - 1);
        int yc = min(max(ty[t], 0), H0 - 1);
        float ww = valid ? tw[t] : 0.f;
        int off = yc * W0 + xc;
        acc0 += ib[off] * ww;
        acc1 += ib[(size_t)HW0 + off] * ww;
        acc2 += ib[(size_t)2 * HW0 + off] * ww;
    }
    const float* ia = imgA + (size_t)b * 3 * HW0;
    int off = y * W0 + x;
    float m = (fabsf(ia[off] - acc0) +
               fabsf(ia[(size_t)HW0 + off] - acc1) +
               fabsf(ia[(size_t)2 * HW0 + off] - acc2)) * (1.f / 3.f);
    mout[idx] = m;
}

// jax-f32 linspace bit path + endpoint forcing (validated round 6).
__device__ inline void ac32_iota(int i, int n_in, int n_out, float delta,
                                 int& i0, int& i1, float& fr) {
    float v = (i == n_out - 1) ? (float)(n_in - 1) : __fmul_rn(delta, (float)i);
    float f0 = floorf(v);
    i0 = (int)f0;
    i1 = min(i0 + 1, n_in - 1);
    fr = __fsub_rn(v, f0);
}

// Unfused pinned f32 bilinear (validated round 6).
__device__ inline float bilerp32(const float* __restrict__ s, int Win,
                                 int y0, int y1, int x0, int x1,
                                 float wy, float wx) {
    float a = s[y0 * Win + x0], b = s[y1 * Win + x0];
    float c = s[y0 * Win + x1], d = s[y1 * Win + x1];
    float omwy = __fsub_rn(1.0f, wy), omwx = __fsub_rn(1.0f, wx);
    float r0 = __fadd_rn(__fmul_rn(a, omwy), __fmul_rn(b, wy));
    float r1 = __fadd_rn(__fmul_rn(c, omwy), __fmul_rn(d, wy));
    return __fadd_rn(__fmul_rn(r0, omwx), __fmul_rn(r1, wx));
}

// chunked XCD swizzle (grid divisible by 8)
__device__ inline int swz_block(int bid, int nblk) {
    int cpx = nblk >> 3;
    return (bid & 7) * cpx + (bid >> 3);
}

// ---------------------------------------------------------------------------
// Shared tap geometry — EXACT round-6 bit paths (validated).
// ---------------------------------------------------------------------------
template<int LVL, int D>
struct Geo {
    int   tx[4], ty[4];
    float tw[4];
    bool  reg;
    int   ry0, ry1, rx0, rx1;
    float wy, wx;
};

template<int LVL, int D>
__device__ inline Geo<LVL, D> geom(int x, int y, int b, int h, int w,
                                   const float* __restrict__ flow,
                                   float scale, float dly, float dlx) {
    Geo<LVL, D> g;
    float gx, gy, x0f, y0f, x1f, y1f;
    if constexpr (LVL == 0) {
        const float* fb = flow + (size_t)b * 2 * HW0;
        float fx = 0.5f * fb[y * W0 + x];
        float fy = 0.5f * fb[(size_t)HW0 + y * W0 + x];
        gx = (float)x + fx;
        gy = (float)y + fy;
        x0f = floorf(gx); y0f = floorf(gy);
        x1f = x0f + 1.f;  y1f = y0f + 1.f;
        g.tw[0] = (x1f - gx) * (y1f - gy); g.tw[1] = (gx - x0f) * (y1f - gy);
        g.tw[2] = (x1f - gx) * (gy - y0f); g.tw[3] = (gx - x0f) * (gy - y0f);
    } else {
        ac32_iota(y, H0, h, dly, g.ry0, g.ry1, g.wy);
        ac32_iota(x, W0, w, dlx, g.rx0, g.rx1, g.wx);
        const float* fB = flow + (size_t)b * 2 * HW0;
        float fx = __fmul_rn(bilerp32(fB, W0, g.ry0, g.ry1, g.rx0, g.rx1, g.wy, g.wx), scale);
        float fy = __fmul_rn(bilerp32(fB + (size_t)HW0, W0, g.ry0, g.ry1, g.rx0, g.rx1, g.wy, g.wx), scale);
        gx = __fadd_rn((float)x, fx);
        gy = __fadd_rn((float)y, fy);
        x0f = floorf(gx); y0f = floorf(gy);
        x1f = __fadd_rn(x0f, 1.0f); y1f = __fadd_rn(y0f, 1.0f);
        float dx0 = __fsub_rn(x1f, gx), dx1 = __fsub_rn(gx, x0f);
        float dy0 = __fsub_rn(y1f, gy), dy1 = __fsub_rn(gy, y0f);
        g.tw[0] = __fmul_rn(dx0, dy0); g.tw[1] = __fmul_rn(dx1, dy0);
        g.tw[2] = __fmul_rn(dx0, dy1); g.tw[3] = __fmul_rn(dx1, dy1);
    }
    int x0 = (int)x0f, y0 = (int)y0f;
    g.tx[0] = x0;     g.tx[1] = x0 + 1; g.tx[2] = x0;     g.tx[3] = x0 + 1;
    g.ty[0] = y0;     g.ty[1] = y0;     g.ty[2] = y0 + 1; g.ty[3] = y0 + 1;
    g.reg = (x0 >= x - D) && (x0 + 1 <= x + D) && (y0 >= y - D) && (y0 + 1 <= y + D);
    return g;
}

// ---------------------------------------------------------------------------
// Irregular-source list: sources with |disp|>D and >=1 valid tap.
// ---------------------------------------------------------------------------
template<int LVL, int D, int H, int W>
__global__ __launch_bounds__(256) void irr_kernel(const float* __restrict__ flow,
                                                  int* __restrict__ cnt,
                                                  int* __restrict__ list,
                                                  float scale, float dly, float dlx) {
    int idx = blockIdx.x * 256 + threadIdx.x;
    if (idx >= Bn * H * W) return;
    int x = idx % W, y = (idx / W) % H, b = idx / (H * W);
    Geo<LVL, D> g = geom<LVL, D>(x, y, b, H, W, flow, scale, dly, dlx);
    if (g.reg) return;
    bool any = false;
#pragma unroll
    for (int t = 0; t < 4; ++t)
        any = any || ((g.tx[t] >= 0) && (g.tx[t] < W) && (g.ty[t] >= 0) && (g.ty[t] < H));
    if (!any) return;
    int pos = atomicAdd(cnt, 1);
    if (pos < IRRCAP) list[pos] = (b << 18) | (y * W + x);
}

// ---------------------------------------------------------------------------
// NCHW -> NHWC transpose (values only; pure copy, bit-exact). CH = padded
// channel count (mult of 4). src0: C0 channels, src1: C1 channels, pad zeros.
// ---------------------------------------------------------------------------
template<int CH>
__global__ __launch_bounds__(256) void transpose_kernel(const float* __restrict__ src0, int C0,
                                                        const float* __restrict__ src1, int C1,
                                                        float* __restrict__ dst, int HW) {
    __shared__ float lds[128 * CH];
    int gp = blockIdx.x * 128;
    int b = gp / HW, p0 = gp % HW;
    int tid = threadIdx.x;
    int CT = C0 + C1;
    for (int i = tid; i < 128 * CH; i += 256) {
        int c = i / 128, p = i % 128;
        float v = 0.f;
        if (c < C0) v = src0[((size_t)b * C0 + c) * HW + p0 + p];
        else if (c < CT) v = src1[((size_t)b * C1 + (c - C0)) * HW + p0 + p];
        lds[p * CH + c] = v;
    }
    __syncthreads();
    float4* d4 = (float4*)(dst + (size_t)gp * CH);
    const int N4 = 128 * CH / 4;
    for (int i = tid; i < N4; i += 256) {
        int base = i * 4;
        float4 q = { lds[base], lds[base + 1], lds[base + 2], lds[base + 3] };
        d4[i] = q;   // lds flat [p][c] == NHWC flat layout
    }
}

// ---------------------------------------------------------------------------
// Gather one binned source into register accumulators. Bit path = round-6.
// ---------------------------------------------------------------------------
template<int LVL, int D, int H, int W, int CBT4, int NVM>
__device__ inline void gather_one(int sidx, int b, int px, int py, int voff, int nv,
        const float* __restrict__ flow, const float* __restrict__ met, float a,
        float scale, float dly, float dlx, const float4* __restrict__ nhwc,
        float (&ax)[NVM], float (&ay)[NVM], float (&az)[NVM], float (&aw)[NVM],
        float& wacc) {
    int sx = sidx % W, sy = sidx / W;
    Geo<LVL, D> g = geom<LVL, D>(sx, sy, b, H, W, flow, scale, dly, dlx);
    int ddx = px - g.tx[0], ddy = py - g.ty[0];
    if (((unsigned)ddx > 1u) || ((unsigned)ddy > 1u)) return;   // overflow-path filter
    int t = ddy * 2 + ddx;
    float wgt;
    if constexpr (LVL == 0) wgt = expf(a * met[(size_t)b * HW0 + sy * W0 + sx]);
    else {
        float m = bilerp32(met + (size_t)b * HW0, W0, g.ry0, g.ry1, g.rx0, g.rx1, g.wy, g.wx);
        wgt = expf(__fmul_rn(a, m));
    }
    float tw = (t == 0) ? g.tw[0] : (t == 1) ? g.tw[1] : (t == 2) ? g.tw[2] : g.tw[3];
    float twv = (LVL == 0) ? tw * wgt : __fmul_rn(wgt, tw);
    wacc += twv;
    const float4* vp = nhwc + ((size_t)b * (H * W) + sidx) * CBT4 + voff;
#pragma unroll
    for (int vi = 0; vi < NVM; ++vi) {
        if (vi >= nv) break;
        float4 q = vp[vi];
        if constexpr (LVL == 0) {
            ax[vi] += q.x * twv; ay[vi] += q.y * twv;
            az[vi] += q.z * twv; aw[vi] += q.w * twv;
        } else {
            ax[vi] += __fmul_rn(__fmul_rn(q.x, wgt), tw);
            ay[vi] += __fmul_rn(__fmul_rn(q.y, wgt), tw);
            az[vi] += __fmul_rn(__fmul_rn(q.z, wgt), tw);
            aw[vi] += __fmul_rn(__fmul_rn(q.w, wgt), tw);
        }
    }
}

// ---------------------------------------------------------------------------
// Bin + gather splat. Block = 16x16 tile. Phase1: bin window sources (and
// irregular-list sources) by destination cell into LDS. Phase2: thread =
// (pixel, channel-half) register-gathers its ~4 entries, normalizes, writes
// NCHW. Zero value atomics; no output memset needed.
// ---------------------------------------------------------------------------
template<int LVL, int CREAL, int CBT4, int NV0, int NV1, int D, int H, int W>
__global__ __launch_bounds__(512) void gather_kernel(
        const float* __restrict__ flow, const float* __restrict__ met,
        const float4* __restrict__ nhwc, const float* __restrict__ alphap,
        const int* __restrict__ irrn_p, const int* __restrict__ irrlist,
        int* __restrict__ ovn_p, int* __restrict__ ovlist,
        float* __restrict__ outp, int Cout, int cbase,
        float scale, float dly, float dlx) {
    constexpr int TW = 16, TH = 16;
    constexpr int NBX = TW + 1, NB = NBX * (TH + 1);
    constexpr int NVM = (NV0 > NV1) ? NV0 : NV1;
    constexpr int HW_ = H * W;
    __shared__ int bcnt[NB];
    __shared__ int bsrc[NB * KB];
    __shared__ int s_irrn, s_ovn;

    const int tilesX = W / TW, tilesY = H / TH;
    int s = swz_block(blockIdx.x, gridDim.x);
    int tpb = tilesX * tilesY;
    int b = s / tpb, r = s % tpb;
    int ty0 = (r / tilesX) * TH, tx0 = (r % tilesX) * TW;
    int tid = threadIdx.x;

    for (int i = tid; i < NB; i += 512) bcnt[i] = 0;
    if (tid == 0) s_irrn = irrn_p[0];
    __syncthreads();

    // ---- phase 1a: window scan, bin regular sources by cell ----
    constexpr int WH = TH + 2 * D, WW2 = TW + 2 * D;
    int wy0 = ty0 - D, wx0 = tx0 - D;
    for (int i = tid; i < WH * WW2; i += 512) {
        int sy = wy0 + i / WW2, sx = wx0 + i % WW2;
        if (sy < 0 || sy >= H || sx < 0 || sx >= W) continue;
        Geo<LVL, D> g = geom<LVL, D>(sx, sy, b, H, W, flow, scale, dly, dlx);
        if (!g.reg) continue;
        int cx = g.tx[0], cy = g.ty[0];
        if (cx < tx0 - 1 || cx > tx0 + TW - 1 || cy < ty0 - 1 || cy > ty0 + TH - 1) continue;
        int bin = (cy - (ty0 - 1)) * NBX + (cx - (tx0 - 1));
        int pos = atomicAdd(&bcnt[bin], 1);
        int sidx = sy * W + sx;
        if (pos < KB) bsrc[bin * KB + pos] = sidx;
        else {
            int p2 = atomicAdd(ovn_p, 1);
            if (p2 < OVCAP) { atomicExch(&ovlist[2 * p2], s); atomicExch(&ovlist[2 * p2 + 1], sidx); }
        }
    }
    // ---- phase 1b: bin irregular sources from global list ----
    int ni = min(s_irrn, IRRCAP);
    for (int i = tid; i < ni; i += 512) {
        int e = irrlist[i];
        if ((e >> 18) != b) continue;
        int sidx = e & ((1 << 18) - 1);
        int sx = sidx % W, sy = sidx / W;
        Geo<LVL, D> g = geom<LVL, D>(sx, sy, b, H, W, flow, scale, dly, dlx);
        int cx = g.tx[0], cy = g.ty[0];
        if (cx < tx0 - 1 || cx > tx0 + TW - 1 || cy < ty0 - 1 || cy > ty0 + TH - 1) continue;
        int bin = (cy - (ty0 - 1)) * NBX + (cx - (tx0 - 1));
        int pos = atomicAdd(&bcnt[bin], 1);
        if (pos < KB) bsrc[bin * KB + pos] = sidx;
        else {
            int p2 = atomicAdd(ovn_p, 1);
            if (p2 < OVCAP) { atomicExch(&ovlist[2 * p2], s); atomicExch(&ovlist[2 * p2 + 1], sidx); }
        }
    }
    __syncthreads();
    if (tid == 0) s_ovn = atomicAdd(ovn_p, 0);
    __syncthreads();

    // ---- phase 2: per (pixel, half) register gather ----
    float a = alphap[0];
    int pixel = tid & 255, half = tid >> 8;
    int px = tx0 + (pixel & 15), py = ty0 + (pixel >> 4);
    int voff = half ? NV0 : 0;
    int nv = half ? NV1 : NV0;
    float ax[NVM], ay[NVM], az[NVM], aw[NVM];
#pragma unroll
    for (int vi = 0; vi < NVM; ++vi) { ax[vi] = 0.f; ay[vi] = 0.f; az[vi] = 0.f; aw[vi] = 0.f; }
    float wacc = 0.f;

#pragma unroll
    for (int cyi = 0; cyi < 2; ++cyi)
#pragma unroll
    for (int cxi = 0; cxi < 2; ++cxi) {
        int cx = px - 1 + cxi, cy = py - 1 + cyi;
        int bin = (cy - (ty0 - 1)) * NBX + (cx - (tx0 - 1));
        int n = min(bcnt[bin], KB);
        for (int j = 0; j < n; ++j)
            gather_one<LVL, D, H, W, CBT4, NVM>(bsrc[bin * KB + j], b, px, py, voff, nv,
                flow, met, a, scale, dly, dlx, nhwc, ax, ay, az, aw, wacc);
    }
    int novr = min(s_ovn, OVCAP);
    for (int j = 0; j < novr; ++j) {
        if (atomicAdd(&ovlist[2 * j], 0) != s) continue;
        int sidx = atomicAdd(&ovlist[2 * j + 1], 0);
        gather_one<LVL, D, H, W, CBT4, NVM>(sidx, b, px, py, voff, nv,
            flow, met, a, scale, dly, dlx, nhwc, ax, ay, az, aw, wacc);
    }

    float denom = wacc + 1e-7f;
    size_t obase = ((size_t)b * Cout + cbase) * HW_ + (py * W + px);
#pragma unroll
    for (int vi = 0; vi < NVM; ++vi) {
        if (vi >= nv) break;
        int c0 = (voff + vi) * 4;
        if (c0 + 0 < CREAL) outp[obase + (size_t)(c0 + 0) * HW_] = ax[vi] / denom;
        if (c0 + 1 < CREAL) outp[obase + (size_t)(c0 + 1) * HW_] = ay[vi] / denom;
        if (c0 + 2 < CREAL) outp[obase + (size_t)(c0 + 2) * HW_] = az[vi] / denom;
        if (c0 + 3 < CREAL) outp[obase + (size_t)(c0 + 3) * HW_] = aw[vi] / denom;
    }
}

inline int nblk(long long n) { return (int)((n + 255) / 256); }

} // namespace

extern "C" void kernel_launch(void* const* d_in, const int* in_sizes, int n_in,
                              void* d_out, int out_size, void* d_ws, size_t ws_size,
                              hipStream_t stream) {
    const float* img1 = (const float*)d_in[0];
    const float* img2 = (const float*)d_in[1];
    const float* f1_1 = (const float*)d_in[2];
    const float* f1_2 = (const float*)d_in[3];
    const float* f1_3 = (const float*)d_in[4];
    const float* f2_1 = (const float*)d_in[5];
    const float* f2_2 = (const float*)d_in[6];
    const float* f2_3 = (const float*)d_in[7];
    const float* fl12 = (const float*)d_in[8];
    const float* fl21 = (const float*)d_in[9];
    const float* alpha = (const float*)d_in[10];
    float* out = (float*)d_out;

    const float dy1 = (float)(H0 - 1) / (float)(H1 - 1);
    const float dx1 = (float)(W0 - 1) / (float)(W1 - 1);
    const float dy2 = (float)(H0 - 1) / (float)(H2 - 1);
    const float dx2 = (float)(W0 - 1) / (float)(W2 - 1);

    // ---- workspace layout ----
    float* ws = (float*)d_ws;
    float* m12 = ws;                                  // Bn*HW0
    float* m21 = m12 + (size_t)Bn * HW0;              // Bn*HW0
    int*   cnt = (int*)(m21 + (size_t)Bn * HW0);      // 16 ints: [0..5] irr, [6..11] ov
    int*   irrlist = cnt + 16;                        // IRRCAP
    int*   ovlist  = irrlist + IRRCAP;                // 2*OVCAP
    float* nhwcW = (float*)(ovlist + 2 * OVCAP);      // L1/L2 NHWC scratch (<=29.4MB)

    // output sub-tensors
    float* l1 = out;                                  // (B,70,256,448)
    float* l2 = l1 + (size_t)Bn * 70 * HW0;           // (B,128,128,224)
    // L0 NHWC (66MB) lives in the not-yet-written l2+l3 region (80.7MB)
    float* nhwc0 = l2;
    float* l3 = l2 + (size_t)Bn * 128 * (H1 * W1);

    hipMemsetAsync(cnt, 0, 16 * sizeof(int), stream);

    metric_kernel<<<nblk((long long)Bn * HW0), 256, 0, stream>>>(img1, img2, fl12, m12);
    metric_kernel<<<nblk((long long)Bn * HW0), 256, 0, stream>>>(img2, img1, fl21, m21);

    const int GI0 = Bn * HW0 / 256;            // 1792
    const int GI1 = Bn * H1 * W1 / 256;        // 448
    const int GI2 = Bn * H2 * W2 / 256;        // 112
    const int GT0 = Bn * HW0 / 128;            // 3584
    const int GT1 = Bn * H1 * W1 / 128;        // 896
    const int GT2 = Bn * H2 * W2 / 128;        // 224
    const int GG0 = Bn * (H0 / 16) * (W0 / 16);  // 1792
    const int GG1 = Bn * (H1 / 16) * (W1 / 16);  // 448
    const int GG2 = Bn * (H2 / 16) * (W2 / 16);  // 112

    // ================= level 0 (D=16, 36-ch NHWC: img(3)+feat(32)+pad) =====
    irr_kernel<0, 16, H0, W0><<<GI0, 256, 0, stream>>>(fl12, cnt + 0, irrlist, 0.f, 0.f, 0.f);
    transpose_kernel<36><<<GT0, 256, 0, stream>>>(img1, 3, f1_1, 32, nhwc0, HW0);
    gather_kernel<0, 35, 9, 5, 4, 16, H0, W0><<<GG0, 512, 0, stream>>>(
        fl12, m12, (const float4*)nhwc0, alpha, cnt + 0, irrlist, cnt + 6, ovlist,
        l1, 70, 0, 0.f, 0.f, 0.f);
    irr_kernel<0, 16, H0, W0><<<GI0, 256, 0, stream>>>(fl21, cnt + 1, irrlist, 0.f, 0.f, 0.f);
    transpose_kernel<36><<<GT0, 256, 0, stream>>>(img2, 3, f2_1, 32, nhwc0, HW0);
    gather_kernel<0, 35, 9, 5, 4, 16, H0, W0><<<GG0, 512, 0, stream>>>(
        fl21, m21, (const float4*)nhwc0, alpha, cnt + 1, irrlist, cnt + 7, ovlist,
        l1, 70, 35, 0.f, 0.f, 0.f);

    // ================= level 1 (D=8, 64-ch NHWC) ===========================
    irr_kernel<1, 8, H1, W1><<<GI1, 256, 0, stream>>>(fl12, cnt + 2, irrlist, 0.25f, dy1, dx1);
    transpose_kernel<64><<<GT1, 256, 0, stream>>>(f1_2, 64, nullptr, 0, nhwcW, H1 * W1);
    gather_kernel<1, 64, 16, 8, 8, 8, H1, W1><<<GG1, 512, 0, stream>>>(
        fl12, m12, (const float4*)nhwcW, alpha, cnt + 2, irrlist, cnt + 8, ovlist,
        l2, 128, 0, 0.25f, dy1, dx1);
    irr_kernel<1, 8, H1, W1><<<GI1, 256, 0, stream>>>(fl21, cnt + 3, irrlist, 0.25f, dy1, dx1);
    transpose_kernel<64><<<GT1, 256, 0, stream>>>(f2_2, 64, nullptr, 0, nhwcW, H1 * W1);
    gather_kernel<1, 64, 16, 8, 8, 8, H1, W1><<<GG1, 512, 0, stream>>>(
        fl21, m21, (const float4*)nhwcW, alpha, cnt + 3, irrlist, cnt + 9, ovlist,
        l2, 128, 64, 0.25f, dy1, dx1);

    // ================= level 2 (D=8, 96-ch NHWC) ===========================
    irr_kernel<1, 8, H2, W2><<<GI2, 256, 0, stream>>>(fl12, cnt + 4, irrlist, 0.125f, dy2, dx2);
    transpose_kernel<96><<<GT2, 256, 0, stream>>>(f1_3, 96, nullptr, 0, nhwcW, H2 * W2);
    gather_kernel<1, 96, 24, 12, 12, 8, H2, W2><<<GG2, 512, 0, stream>>>(
        fl12, m12, (const float4*)nhwcW, alpha, cnt + 4, irrlist, cnt + 10, ovlist,
        l3, 192, 0, 0.125f, dy2, dx2);
    irr_kernel<1, 8, H2, W2><<<GI2, 256, 0, stream>>>(fl21, cnt + 5, irrlist, 0.125f, dy2, dx2);
    transpose_kernel<96><<<GT2, 256, 0, stream>>>(f2_3, 96, nullptr, 0, nhwcW, H2 * W2);
    gather_kernel<1, 96, 24, 12, 12, 8, H2, W2><<<GG2, 512, 0, stream>>>(
        fl21, m21, (const float4*)nhwcW, alpha, cnt + 5, irrlist, cnt + 11, ovlist,
        l3, 192, 96, 0.125f, dy2, dx2);
}

// Round 16
// 504.635 us; speedup vs baseline: 3.1318x; 1.1847x over previous
//
#include <hip/hip_runtime.h>
#include <math.h>

namespace {

constexpr int Bn = 4;
constexpr int H0 = 256, W0 = 448;
constexpr int H1 = 128, W1 = 224;
constexpr int H2 = 64,  W2 = 112;
constexpr int HW0 = H0 * W0;
constexpr int IRRCAP = 8192;
constexpr int OVCAP  = 4096;
constexpr int KB = 10;     // bin capacity; P(Poisson(1) > 10) ~ 8e-9 -> overflow ~never

// np.linspace(-1+1/n, 1-1/n, n, dtype=f32) bit path (backwarp side; validated).
__device__ inline float lin_ac_f32(int i, int n) {
    if (i == n - 1) return (float)(1.0 - 1.0 / (double)n);
    double start = -1.0 + 1.0 / (double)n;
    double step  = (2.0 - 2.0 / (double)n) / (double)(n - 1);
    return (float)(start + (double)i * step);
}

// ---------------------------------------------------------------------------
// Backwarp + L1 occlusion metric (validated, unchanged).
// ---------------------------------------------------------------------------
__global__ void metric_kernel(const float* __restrict__ imgA,
                              const float* __restrict__ imgB,
                              const float* __restrict__ flow,
                              float* __restrict__ mout) {
    int idx = blockIdx.x * blockDim.x + threadIdx.x;
    int total = Bn * HW0;
    if (idx >= total) return;
    int x = idx % W0;
    int y = (idx / W0) % H0;
    int b = idx / HW0;

    const float* fb = flow + (size_t)b * 2 * HW0;
    float fx = fb[y * W0 + x];
    float fy = fb[(size_t)HW0 + y * W0 + x];

    const float sxc = (float)(2.0 / (double)(W0 - 1));
    const float syc = (float)(2.0 / (double)(H0 - 1));
    float gx = __fadd_rn(lin_ac_f32(x, W0), __fmul_rn(fx, sxc));
    float gy = __fadd_rn(lin_ac_f32(y, H0), __fmul_rn(fy, syc));
    float px = __fmul_rn(__fmul_rn(__fadd_rn(gx, 1.0f), 0.5f), (float)(W0 - 1));
    float py = __fmul_rn(__fmul_rn(__fadd_rn(gy, 1.0f), 0.5f), (float)(H0 - 1));

    float x0f = floorf(px), y0f = floorf(py);
    float x1f = x0f + 1.0f, y1f = y0f + 1.0f;
    int x0 = (int)x0f, y0 = (int)y0f, x1 = (int)x1f, y1 = (int)y1f;

    float tw[4] = { (x1f - px) * (y1f - py), (px - x0f) * (y1f - py),
                    (x1f - px) * (py - y0f), (px - x0f) * (py - y0f) };
    int tx[4] = { x0, x1, x0, x1 };
    int ty[4] = { y0, y0, y1, y1 };

    const float* ib = imgB + (size_t)b * 3 * HW0;
    float acc0 = 0.f, acc1 = 0.f, acc2 = 0.f;
#pragma unroll
    for (int t = 0; t < 4; ++t) {
        bool valid = (tx[t] >= 0) && (tx[t] < W0) && (ty[t] >= 0) && (ty[t] < H0);
        int xc = min(max(tx[t], 0), W0 - 1);
        int yc = min(max(ty[t], 0), H0 - 1);
        float ww = valid ? tw[t] : 0.f;
        int off = yc * W0 + xc;
        acc0 += ib[off] * ww;
        acc1 += ib[(size_t)HW0 + off] * ww;
        acc2 += ib[(size_t)2 * HW0 + off] * ww;
    }
    const float* ia = imgA + (size_t)b * 3 * HW0;
    int off = y * W0 + x;
    float m = (fabsf(ia[off] - acc0) +
               fabsf(ia[(size_t)HW0 + off] - acc1) +
               fabsf(ia[(size_t)2 * HW0 + off] - acc2)) * (1.f / 3.f);
    mout[idx] = m;
}

// jax-f32 linspace bit path + endpoint forcing (validated round 6).
__device__ inline void ac32_iota(int i, int n_in, int n_out, float delta,
                                 int& i0, int& i1, float& fr) {
    float v = (i == n_out - 1) ? (float)(n_in - 1) : __fmul_rn(delta, (float)i);
    float f0 = floorf(v);
    i0 = (int)f0;
    i1 = min(i0 + 1, n_in - 1);
    fr = __fsub_rn(v, f0);
}

// Unfused pinned f32 bilinear (validated round 6).
__device__ inline float bilerp32(const float* __restrict__ s, int Win,
                                 int y0, int y1, int x0, int x1,
                                 float wy, float wx) {
    float a = s[y0 * Win + x0], b = s[y1 * Win + x0];
    float c = s[y0 * Win + x1], d = s[y1 * Win + x1];
    float omwy = __fsub_rn(1.0f, wy), omwx = __fsub_rn(1.0f, wx);
    float r0 = __fadd_rn(__fmul_rn(a, omwy), __fmul_rn(b, wy));
    float r1 = __fadd_rn(__fmul_rn(c, omwy), __fmul_rn(d, wy));
    return __fadd_rn(__fmul_rn(r0, omwx), __fmul_rn(r1, wx));
}

// chunked XCD swizzle (grid divisible by 8)
__device__ inline int swz_block(int bid, int nblk) {
    int cpx = nblk >> 3;
    return (bid & 7) * cpx + (bid >> 3);
}

// ---------------------------------------------------------------------------
// Shared tap geometry — EXACT round-6 bit paths (validated). gx/gy exposed
// so phase-2 can recompute tap weights bit-identically.
// ---------------------------------------------------------------------------
template<int LVL, int D>
struct Geo {
    int   tx[4], ty[4];
    float tw[4];
    float gx, gy;
    bool  reg;
    int   ry0, ry1, rx0, rx1;
    float wy, wx;
};

template<int LVL, int D>
__device__ inline Geo<LVL, D> geom(int x, int y, int b, int h, int w,
                                   const float* __restrict__ flow,
                                   float scale, float dly, float dlx) {
    Geo<LVL, D> g;
    float gx, gy, x0f, y0f, x1f, y1f;
    if constexpr (LVL == 0) {
        const float* fb = flow + (size_t)b * 2 * HW0;
        float fx = 0.5f * fb[y * W0 + x];
        float fy = 0.5f * fb[(size_t)HW0 + y * W0 + x];
        gx = (float)x + fx;
        gy = (float)y + fy;
        x0f = floorf(gx); y0f = floorf(gy);
        x1f = x0f + 1.f;  y1f = y0f + 1.f;
        g.tw[0] = (x1f - gx) * (y1f - gy); g.tw[1] = (gx - x0f) * (y1f - gy);
        g.tw[2] = (x1f - gx) * (gy - y0f); g.tw[3] = (gx - x0f) * (gy - y0f);
    } else {
        ac32_iota(y, H0, h, dly, g.ry0, g.ry1, g.wy);
        ac32_iota(x, W0, w, dlx, g.rx0, g.rx1, g.wx);
        const float* fB = flow + (size_t)b * 2 * HW0;
        float fx = __fmul_rn(bilerp32(fB, W0, g.ry0, g.ry1, g.rx0, g.rx1, g.wy, g.wx), scale);
        float fy = __fmul_rn(bilerp32(fB + (size_t)HW0, W0, g.ry0, g.ry1, g.rx0, g.rx1, g.wy, g.wx), scale);
        gx = __fadd_rn((float)x, fx);
        gy = __fadd_rn((float)y, fy);
        x0f = floorf(gx); y0f = floorf(gy);
        x1f = __fadd_rn(x0f, 1.0f); y1f = __fadd_rn(y0f, 1.0f);
        float dx0 = __fsub_rn(x1f, gx), dx1 = __fsub_rn(gx, x0f);
        float dy0 = __fsub_rn(y1f, gy), dy1 = __fsub_rn(gy, y0f);
        g.tw[0] = __fmul_rn(dx0, dy0); g.tw[1] = __fmul_rn(dx1, dy0);
        g.tw[2] = __fmul_rn(dx0, dy1); g.tw[3] = __fmul_rn(dx1, dy1);
    }
    g.gx = gx; g.gy = gy;
    int x0 = (int)x0f, y0 = (int)y0f;
    g.tx[0] = x0;     g.tx[1] = x0 + 1; g.tx[2] = x0;     g.tx[3] = x0 + 1;
    g.ty[0] = y0;     g.ty[1] = y0;     g.ty[2] = y0 + 1; g.ty[3] = y0 + 1;
    g.reg = (x0 >= x - D) && (x0 + 1 <= x + D) && (y0 >= y - D) && (y0 + 1 <= y + D);
    return g;
}

// ---------------------------------------------------------------------------
// Irregular-source list: sources with |disp|>D and >=1 valid tap.
// ---------------------------------------------------------------------------
template<int LVL, int D, int H, int W>
__global__ __launch_bounds__(256) void irr_kernel(const float* __restrict__ flow,
                                                  int* __restrict__ cnt,
                                                  int* __restrict__ list,
                                                  float scale, float dly, float dlx) {
    int idx = blockIdx.x * 256 + threadIdx.x;
    if (idx >= Bn * H * W) return;
    int x = idx % W, y = (idx / W) % H, b = idx / (H * W);
    Geo<LVL, D> g = geom<LVL, D>(x, y, b, H, W, flow, scale, dly, dlx);
    if (g.reg) return;
    bool any = false;
#pragma unroll
    for (int t = 0; t < 4; ++t)
        any = any || ((g.tx[t] >= 0) && (g.tx[t] < W) && (g.ty[t] >= 0) && (g.ty[t] < H));
    if (!any) return;
    int pos = atomicAdd(cnt, 1);
    if (pos < IRRCAP) list[pos] = (b << 18) | (y * W + x);
}

// ---------------------------------------------------------------------------
// NCHW -> NHWC transpose (values only; pure copy, bit-exact).
// ---------------------------------------------------------------------------
template<int CH>
__global__ __launch_bounds__(256) void transpose_kernel(const float* __restrict__ src0, int C0,
                                                        const float* __restrict__ src1, int C1,
                                                        float* __restrict__ dst, int HW) {
    __shared__ float lds[128 * CH];
    int gp = blockIdx.x * 128;
    int b = gp / HW, p0 = gp % HW;
    int tid = threadIdx.x;
    int CT = C0 + C1;
    for (int i = tid; i < 128 * CH; i += 256) {
        int c = i / 128, p = i % 128;
        float v = 0.f;
        if (c < C0) v = src0[((size_t)b * C0 + c) * HW + p0 + p];
        else if (c < CT) v = src1[((size_t)b * C1 + (c - C0)) * HW + p0 + p];
        lds[p * CH + c] = v;
    }
    __syncthreads();
    float4* d4 = (float4*)(dst + (size_t)gp * CH);
    const int N4 = 128 * CH / 4;
    for (int i = tid; i < N4; i += 256) {
        int base = i * 4;
        float4 q = { lds[base], lds[base + 1], lds[base + 2], lds[base + 3] };
        d4[i] = q;
    }
}

// ---------------------------------------------------------------------------
// Full-recompute gather (overflow path only; rare). Bit path = round-6.
// ---------------------------------------------------------------------------
template<int LVL, int D, int H, int W, int CBT4, int NVM>
__device__ inline void gather_one(int sidx, int b, int px, int py, int voff, int nv,
        const float* __restrict__ flow, const float* __restrict__ met, float a,
        float scale, float dly, float dlx, const float4* __restrict__ nhwc,
        float (&ax)[NVM], float (&ay)[NVM], float (&az)[NVM], float (&aw)[NVM],
        float& wacc) {
    int sx = sidx % W, sy = sidx / W;
    Geo<LVL, D> g = geom<LVL, D>(sx, sy, b, H, W, flow, scale, dly, dlx);
    int ddx = px - g.tx[0], ddy = py - g.ty[0];
    if (((unsigned)ddx > 1u) || ((unsigned)ddy > 1u)) return;
    int t = ddy * 2 + ddx;
    float wgt;
    if constexpr (LVL == 0) wgt = expf(a * met[(size_t)b * HW0 + sy * W0 + sx]);
    else {
        float m = bilerp32(met + (size_t)b * HW0, W0, g.ry0, g.ry1, g.rx0, g.rx1, g.wy, g.wx);
        wgt = expf(__fmul_rn(a, m));
    }
    float tw = (t == 0) ? g.tw[0] : (t == 1) ? g.tw[1] : (t == 2) ? g.tw[2] : g.tw[3];
    float twv = (LVL == 0) ? tw * wgt : __fmul_rn(wgt, tw);
    wacc += twv;
    const float4* vp = nhwc + ((size_t)b * (H * W) + sidx) * CBT4 + voff;
#pragma unroll
    for (int vi = 0; vi < NVM; ++vi) {
        if (vi >= nv) break;
        float4 q = vp[vi];
        if constexpr (LVL == 0) {
            ax[vi] += q.x * twv; ay[vi] += q.y * twv;
            az[vi] += q.z * twv; aw[vi] += q.w * twv;
        } else {
            ax[vi] += __fmul_rn(__fmul_rn(q.x, wgt), tw);
            ay[vi] += __fmul_rn(__fmul_rn(q.y, wgt), tw);
            az[vi] += __fmul_rn(__fmul_rn(q.z, wgt), tw);
            aw[vi] += __fmul_rn(__fmul_rn(q.w, wgt), tw);
        }
    }
}

// ---------------------------------------------------------------------------
// Bin + gather splat. Phase1 computes per-source wgt ONCE and stores
// {sidx, gx, gy, wgt} (was recomputed 8x/source in phase 2 — the R14
// latency redundancy). Phase2 recomputes the tap weight from stored gx/gy
// with the identical pinned ops (bit-exact), tap index compile-time.
// ---------------------------------------------------------------------------
template<int LVL, int CREAL, int CBT4, int NV0, int NV1, int D, int H, int W>
__global__ __launch_bounds__(512) void gather_kernel(
        const float* __restrict__ flow, const float* __restrict__ met,
        const float4* __restrict__ nhwc, const float* __restrict__ alphap,
        const int* __restrict__ irrn_p, const int* __restrict__ irrlist,
        int* __restrict__ ovn_p, int* __restrict__ ovlist,
        float* __restrict__ outp, int Cout, int cbase,
        float scale, float dly, float dlx) {
    constexpr int TW = 16, TH = 16;
    constexpr int NBX = TW + 1, NB = NBX * (TH + 1);
    constexpr int NVM = (NV0 > NV1) ? NV0 : NV1;
    constexpr int HW_ = H * W;
    __shared__ int   bcnt[NB];
    __shared__ int   bsidx[NB * KB];
    __shared__ float bgx[NB * KB], bgy[NB * KB], bwgt[NB * KB];
    __shared__ int s_irrn, s_ovn;

    const int tilesX = W / TW, tilesY = H / TH;
    int s = swz_block(blockIdx.x, gridDim.x);
    int tpb = tilesX * tilesY;
    int b = s / tpb, r = s % tpb;
    int ty0 = (r / tilesX) * TH, tx0 = (r % tilesX) * TW;
    int tid = threadIdx.x;

    for (int i = tid; i < NB; i += 512) bcnt[i] = 0;
    if (tid == 0) s_irrn = irrn_p[0];
    __syncthreads();

    float a = alphap[0];

    // ---- phase 1a: window scan; bin {sidx,gx,gy,wgt} by destination cell --
    constexpr int WH = TH + 2 * D, WW2 = TW + 2 * D;
    int wy0 = ty0 - D, wx0 = tx0 - D;
    for (int i = tid; i < WH * WW2; i += 512) {
        int sy = wy0 + i / WW2, sx = wx0 + i % WW2;
        if (sy < 0 || sy >= H || sx < 0 || sx >= W) continue;
        Geo<LVL, D> g = geom<LVL, D>(sx, sy, b, H, W, flow, scale, dly, dlx);
        if (!g.reg) continue;
        int cx = g.tx[0], cy = g.ty[0];
        if (cx < tx0 - 1 || cx > tx0 + TW - 1 || cy < ty0 - 1 || cy > ty0 + TH - 1) continue;
        float wgt;
        if constexpr (LVL == 0) wgt = expf(a * met[(size_t)b * HW0 + sy * W0 + sx]);
        else {
            float m = bilerp32(met + (size_t)b * HW0, W0, g.ry0, g.ry1, g.rx0, g.rx1, g.wy, g.wx);
            wgt = expf(__fmul_rn(a, m));
        }
        int bin = (cy - (ty0 - 1)) * NBX + (cx - (tx0 - 1));
        int pos = atomicAdd(&bcnt[bin], 1);
        int sidx = sy * W + sx;
        if (pos < KB) {
            int e = bin * KB + pos;
            bsidx[e] = sidx; bgx[e] = g.gx; bgy[e] = g.gy; bwgt[e] = wgt;
        } else {
            int p2 = atomicAdd(ovn_p, 1);
            if (p2 < OVCAP) { atomicExch(&ovlist[2 * p2], s); atomicExch(&ovlist[2 * p2 + 1], sidx); }
        }
    }
    // ---- phase 1b: bin irregular sources from global list ----
    int ni = min(s_irrn, IRRCAP);
    for (int i = tid; i < ni; i += 512) {
        int e0 = irrlist[i];
        if ((e0 >> 18) != b) continue;
        int sidx = e0 & ((1 << 18) - 1);
        int sx = sidx % W, sy = sidx / W;
        Geo<LVL, D> g = geom<LVL, D>(sx, sy, b, H, W, flow, scale, dly, dlx);
        int cx = g.tx[0], cy = g.ty[0];
        if (cx < tx0 - 1 || cx > tx0 + TW - 1 || cy < ty0 - 1 || cy > ty0 + TH - 1) continue;
        float wgt;
        if constexpr (LVL == 0) wgt = expf(a * met[(size_t)b * HW0 + sy * W0 + sx]);
        else {
            float m = bilerp32(met + (size_t)b * HW0, W0, g.ry0, g.ry1, g.rx0, g.rx1, g.wy, g.wx);
            wgt = expf(__fmul_rn(a, m));
        }
        int bin = (cy - (ty0 - 1)) * NBX + (cx - (tx0 - 1));
        int pos = atomicAdd(&bcnt[bin], 1);
        if (pos < KB) {
            int e = bin * KB + pos;
            bsidx[e] = sidx; bgx[e] = g.gx; bgy[e] = g.gy; bwgt[e] = wgt;
        } else {
            int p2 = atomicAdd(ovn_p, 1);
            if (p2 < OVCAP) { atomicExch(&ovlist[2 * p2], s); atomicExch(&ovlist[2 * p2 + 1], sidx); }
        }
    }
    __syncthreads();
    if (tid == 0) s_ovn = atomicAdd(ovn_p, 0);
    __syncthreads();

    // ---- phase 2: per (pixel, half) register gather ----
    int pixel = tid & 255, half = tid >> 8;
    int px = tx0 + (pixel & 15), py = ty0 + (pixel >> 4);
    int voff = half ? NV0 : 0;
    int nv = half ? NV1 : NV0;
    const float4* nb = nhwc + (size_t)b * HW_ * CBT4 + voff;
    float ax[NVM], ay[NVM], az[NVM], aw[NVM];
#pragma unroll
    for (int vi = 0; vi < NVM; ++vi) { ax[vi] = 0.f; ay[vi] = 0.f; az[vi] = 0.f; aw[vi] = 0.f; }
    float wacc = 0.f;

#pragma unroll
    for (int cyi = 0; cyi < 2; ++cyi)
#pragma unroll
    for (int cxi = 0; cxi < 2; ++cxi) {
        const int t = (1 - cyi) * 2 + (1 - cxi);    // tap index, compile-time
        int cx = px - 1 + cxi, cy = py - 1 + cyi;
        int bin = (cy - (ty0 - 1)) * NBX + (cx - (tx0 - 1));
        int n = min(bcnt[bin], KB);
        for (int j = 0; j < n; ++j) {
            int e = bin * KB + j;
            float gx = bgx[e], gy = bgy[e], wgt = bwgt[e];
            float x0f = floorf(gx), y0f = floorf(gy);
            float tw;
            if constexpr (LVL == 0) {
                float x1f = x0f + 1.f, y1f = y0f + 1.f;
                tw = (t == 0) ? (x1f - gx) * (y1f - gy)
                   : (t == 1) ? (gx - x0f) * (y1f - gy)
                   : (t == 2) ? (x1f - gx) * (gy - y0f)
                              : (gx - x0f) * (gy - y0f);
            } else {
                float x1f = __fadd_rn(x0f, 1.0f), y1f = __fadd_rn(y0f, 1.0f);
                float dx0 = __fsub_rn(x1f, gx), dx1 = __fsub_rn(gx, x0f);
                float dy0 = __fsub_rn(y1f, gy), dy1 = __fsub_rn(gy, y0f);
                tw = (t == 0) ? __fmul_rn(dx0, dy0)
                   : (t == 1) ? __fmul_rn(dx1, dy0)
                   : (t == 2) ? __fmul_rn(dx0, dy1)
                              : __fmul_rn(dx1, dy1);
            }
            const float4* vp = nb + (size_t)bsidx[e] * CBT4;
            if constexpr (LVL == 0) {
                float twv = tw * wgt;
                wacc += twv;
#pragma unroll
                for (int vi = 0; vi < NVM; ++vi) {
                    if (vi >= nv) break;
                    float4 q = vp[vi];
                    ax[vi] += q.x * twv; ay[vi] += q.y * twv;
                    az[vi] += q.z * twv; aw[vi] += q.w * twv;
                }
            } else {
                wacc += __fmul_rn(wgt, tw);
#pragma unroll
                for (int vi = 0; vi < NVM; ++vi) {
                    if (vi >= nv) break;
                    float4 q = vp[vi];
                    ax[vi] += __fmul_rn(__fmul_rn(q.x, wgt), tw);
                    ay[vi] += __fmul_rn(__fmul_rn(q.y, wgt), tw);
                    az[vi] += __fmul_rn(__fmul_rn(q.z, wgt), tw);
                    aw[vi] += __fmul_rn(__fmul_rn(q.w, wgt), tw);
                }
            }
        }
    }
    // overflow entries (expected never at KB=10)
    int novr = min(s_ovn, OVCAP);
    for (int j = 0; j < novr; ++j) {
        if (atomicAdd(&ovlist[2 * j], 0) != s) continue;
        int sidx = atomicAdd(&ovlist[2 * j + 1], 0);
        gather_one<LVL, D, H, W, CBT4, NVM>(sidx, b, px, py, voff, nv,
            flow, met, a, scale, dly, dlx, nhwc, ax, ay, az, aw, wacc);
    }

    float denom = wacc + 1e-7f;
    size_t obase = ((size_t)b * Cout + cbase) * HW_ + (py * W + px);
#pragma unroll
    for (int vi = 0; vi < NVM; ++vi) {
        if (vi >= nv) break;
        int c0 = (voff + vi) * 4;
        if (c0 + 0 < CREAL) outp[obase + (size_t)(c0 + 0) * HW_] = ax[vi] / denom;
        if (c0 + 1 < CREAL) outp[obase + (size_t)(c0 + 1) * HW_] = ay[vi] / denom;
        if (c0 + 2 < CREAL) outp[obase + (size_t)(c0 + 2) * HW_] = az[vi] / denom;
        if (c0 + 3 < CREAL) outp[obase + (size_t)(c0 + 3) * HW_] = aw[vi] / denom;
    }
}

inline int nblk(long long n) { return (int)((n + 255) / 256); }

} // namespace

extern "C" void kernel_launch(void* const* d_in, const int* in_sizes, int n_in,
                              void* d_out, int out_size, void* d_ws, size_t ws_size,
                              hipStream_t stream) {
    const float* img1 = (const float*)d_in[0];
    const float* img2 = (const float*)d_in[1];
    const float* f1_1 = (const float*)d_in[2];
    const float* f1_2 = (const float*)d_in[3];
    const float* f1_3 = (const float*)d_in[4];
    const float* f2_1 = (const float*)d_in[5];
    const float* f2_2 = (const float*)d_in[6];
    const float* f2_3 = (const float*)d_in[7];
    const float* fl12 = (const float*)d_in[8];
    const float* fl21 = (const float*)d_in[9];
    const float* alpha = (const float*)d_in[10];
    float* out = (float*)d_out;

    const float dy1 = (float)(H0 - 1) / (float)(H1 - 1);
    const float dx1 = (float)(W0 - 1) / (float)(W1 - 1);
    const float dy2 = (float)(H0 - 1) / (float)(H2 - 1);
    const float dx2 = (float)(W0 - 1) / (float)(W2 - 1);

    // ---- workspace layout ----
    float* ws = (float*)d_ws;
    float* m12 = ws;
    float* m21 = m12 + (size_t)Bn * HW0;
    int*   cnt = (int*)(m21 + (size_t)Bn * HW0);      // [0..5] irr, [6..11] ov
    int*   irrlist = cnt + 16;
    int*   ovlist  = irrlist + IRRCAP;
    float* nhwcW = (float*)(ovlist + 2 * OVCAP);

    float* l1 = out;
    float* l2 = l1 + (size_t)Bn * 70 * HW0;
    float* nhwc0 = l2;                                // L0 NHWC in unwritten l2+l3
    float* l3 = l2 + (size_t)Bn * 128 * (H1 * W1);

    (void)hipMemsetAsync(cnt, 0, 16 * sizeof(int), stream);

    metric_kernel<<<nblk((long long)Bn * HW0), 256, 0, stream>>>(img1, img2, fl12, m12);
    metric_kernel<<<nblk((long long)Bn * HW0), 256, 0, stream>>>(img2, img1, fl21, m21);

    const int GI0 = Bn * HW0 / 256;
    const int GI1 = Bn * H1 * W1 / 256;
    const int GI2 = Bn * H2 * W2 / 256;
    const int GT0 = Bn * HW0 / 128;
    const int GT1 = Bn * H1 * W1 / 128;
    const int GT2 = Bn * H2 * W2 / 128;
    const int GG0 = Bn * (H0 / 16) * (W0 / 16);
    const int GG1 = Bn * (H1 / 16) * (W1 / 16);
    const int GG2 = Bn * (H2 / 16) * (W2 / 16);

    // ================= level 0 =================
    irr_kernel<0, 16, H0, W0><<<GI0, 256, 0, stream>>>(fl12, cnt + 0, irrlist, 0.f, 0.f, 0.f);
    transpose_kernel<36><<<GT0, 256, 0, stream>>>(img1, 3, f1_1, 32, nhwc0, HW0);
    gather_kernel<0, 35, 9, 5, 4, 16, H0, W0><<<GG0, 512, 0, stream>>>(
        fl12, m12, (const float4*)nhwc0, alpha, cnt + 0, irrlist, cnt + 6, ovlist,
        l1, 70, 0, 0.f, 0.f, 0.f);
    irr_kernel<0, 16, H0, W0><<<GI0, 256, 0, stream>>>(fl21, cnt + 1, irrlist, 0.f, 0.f, 0.f);
    transpose_kernel<36><<<GT0, 256, 0, stream>>>(img2, 3, f2_1, 32, nhwc0, HW0);
    gather_kernel<0, 35, 9, 5, 4, 16, H0, W0><<<GG0, 512, 0, stream>>>(
        fl21, m21, (const float4*)nhwc0, alpha, cnt + 1, irrlist, cnt + 7, ovlist,
        l1, 70, 35, 0.f, 0.f, 0.f);

    // ================= level 1 =================
    irr_kernel<1, 8, H1, W1><<<GI1, 256, 0, stream>>>(fl12, cnt + 2, irrlist, 0.25f, dy1, dx1);
    transpose_kernel<64><<<GT1, 256, 0, stream>>>(f1_2, 64, nullptr, 0, nhwcW, H1 * W1);
    gather_kernel<1, 64, 16, 8, 8, 8, H1, W1><<<GG1, 512, 0, stream>>>(
        fl12, m12, (const float4*)nhwcW, alpha, cnt + 2, irrlist, cnt + 8, ovlist,
        l2, 128, 0, 0.25f, dy1, dx1);
    irr_kernel<1, 8, H1, W1><<<GI1, 256, 0, stream>>>(fl21, cnt + 3, irrlist, 0.25f, dy1, dx1);
    transpose_kernel<64><<<GT1, 256, 0, stream>>>(f2_2, 64, nullptr, 0, nhwcW, H1 * W1);
    gather_kernel<1, 64, 16, 8, 8, 8, H1, W1><<<GG1, 512, 0, stream>>>(
        fl21, m21, (const float4*)nhwcW, alpha, cnt + 3, irrlist, cnt + 9, ovlist,
        l2, 128, 64, 0.25f, dy1, dx1);

    // ================= level 2 =================
    irr_kernel<1, 8, H2, W2><<<GI2, 256, 0, stream>>>(fl12, cnt + 4, irrlist, 0.125f, dy2, dx2);
    transpose_kernel<96><<<GT2, 256, 0, stream>>>(f1_3, 96, nullptr, 0, nhwcW, H2 * W2);
    gather_kernel<1, 96, 24, 12, 12, 8, H2, W2><<<GG2, 512, 0, stream>>>(
        fl12, m12, (const float4*)nhwcW, alpha, cnt + 4, irrlist, cnt + 10, ovlist,
        l3, 192, 0, 0.125f, dy2, dx2);
    irr_kernel<1, 8, H2, W2><<<GI2, 256, 0, stream>>>(fl21, cnt + 5, irrlist, 0.125f, dy2, dx2);
    transpose_kernel<96><<<GT2, 256, 0, stream>>>(f2_3, 96, nullptr, 0, nhwcW, H2 * W2);
    gather_kernel<1, 96, 24, 12, 12, 8, H2, W2><<<GG2, 512, 0, stream>>>(
        fl21, m21, (const float4*)nhwcW, alpha, cnt + 5, irrlist, cnt + 11, ovlist,
        l3, 192, 96, 0.125f, dy2, dx2);
}